// Round 1
// 2083.672 us; speedup vs baseline: 1.1847x; 1.1847x over previous
//
#include <hip/hip_runtime.h>
#include <cstdint>
#include <cstddef>

// ---------------------------------------------------------------------------
// Problem constants
// ---------------------------------------------------------------------------
#define B_SZ 32
#define T_SZ 1024
#define DIN  80
#define H3   256   // encoder output dim
#define FEAT 768   // 3 * H3
#define G4   1024  // 4 * H (LSTM gates)
#define HH   256   // LSTM hidden

typedef __attribute__((ext_vector_type(8))) short short8;   // 8 x bf16 (4 VGPRs)
typedef __attribute__((ext_vector_type(4))) float f32x4;    // MFMA accumulator
typedef __attribute__((ext_vector_type(8))) int v8i;        // 32B fp8 fragment

__device__ inline float bf2f(unsigned short u) {
    return __uint_as_float(((unsigned int)u) << 16);
}
__device__ inline unsigned short f2bf(float f) {
    unsigned int u = __float_as_uint(f);
    u += 0x7fffu + ((u >> 16) & 1u);   // RNE
    return (unsigned short)(u >> 16);
}
// fast sigmoid/tanh: v_exp (exp2) + v_rcp
#define LOG2E 1.4426950408889634f
__device__ inline float sigm(float x) {
    return __builtin_amdgcn_rcpf(1.f + __builtin_amdgcn_exp2f(x * -LOG2E));
}
__device__ inline float tanh_f(float x) {
    return fmaf(2.f, __builtin_amdgcn_rcpf(1.f + __builtin_amdgcn_exp2f(x * (-2.f * LOG2E))), -1.f);
}

// ---------------------------------------------------------------------------
// fp32 -> bf16 conversion (grid-stride)
// ---------------------------------------------------------------------------
__global__ void k_cvt(const float* __restrict__ src, unsigned short* __restrict__ dst, int n) {
    int i = blockIdx.x * blockDim.x + threadIdx.x;
    int stride = gridDim.x * blockDim.x;
    for (; i < n; i += stride) dst[i] = f2bf(src[i]);
}

// ---------------------------------------------------------------------------
// stable argsort by descending length (matches jnp.argsort(-lens), stable)
// ---------------------------------------------------------------------------
__global__ void k_order(const int* __restrict__ lens, int* __restrict__ order,
                        int* __restrict__ lens_sorted, float* __restrict__ out_order) {
    int b = threadIdx.x;
    if (b < B_SZ) {
        int lb = lens[b];
        int r = 0;
        for (int j = 0; j < B_SZ; ++j) {
            int lj = lens[j];
            if (lj > lb || (lj == lb && j < b)) ++r;
        }
        order[r] = b;
        lens_sorted[r] = lb;
        out_order[r] = (float)b;   // second tuple output, as float
    }
}

// rowmap for backward direction: rowmap[bs*1024+t] = bs*1024 + clip(len-1-t, 0, 1023)
__global__ void k_rowmap(const int* __restrict__ lens_sorted, int* __restrict__ rowmap) {
    int idx = blockIdx.x * 256 + threadIdx.x;   // 32768 total
    int bs = idx >> 10, t = idx & 1023;
    int len = lens_sorted[bs];
    int src = len - 1 - t;
    src = src < 0 ? 0 : src;
    rowmap[idx] = (bs << 10) + src;
}

// zero the padded tail: out[bs, t, 0:512] = 0 for t >= len[bs]
__global__ void k_ztail(const int* __restrict__ lens_sorted, float* __restrict__ out) {
    int t = blockIdx.x, bs = blockIdx.y;
    if (t < lens_sorted[bs]) return;
    float4* p = (float4*)(out + ((size_t)bs * T_SZ + t) * 512);
    p[threadIdx.x] = make_float4(0.f, 0.f, 0.f, 0.f);   // 128 threads x 16B
}

// ---------------------------------------------------------------------------
// Whh [1024 rows (n), 256 cols (k)] fp32 -> fp8 e4m3 in MFMA B-fragment order
// for mfma_scale_f32_16x16x128_f8f6f4, with a PERMUTED n-slot assignment so
// that output lane l16 owns ADJACENT gate columns (p=0/1 -> col, col+1):
//   slot (nt, l16): gb = nt>>4, m = nt&15, wave = m>>1, p = m&1
//   gate column n = gb*256 + wave*32 + l16*2 + p
// k mapping unchanged: k = kc*128 + (lane>>4)*32 + j, j = 0..31 contiguous.
// byte addr = ((nt*2 + kc)*64 + lane)*32. One thread per 16-byte half.
// ---------------------------------------------------------------------------
__global__ void k_wfrag8(const float* __restrict__ Whh, unsigned char* __restrict__ dst) {
    int t = blockIdx.x * 256 + threadIdx.x;   // 0..16383
    int lane = t & 63, hf = (t >> 6) & 1, kc = (t >> 7) & 1, nt = t >> 8;
    int l16 = lane & 15;
    int gb = nt >> 4, m = nt & 15, wv = m >> 1, pp = m & 1;
    int n = gb * 256 + wv * 32 + l16 * 2 + pp;     // permuted gate column
    int k0 = kc * 128 + (lane >> 4) * 32 + hf * 16;
    const float* p = Whh + (size_t)n * 256 + k0;
    unsigned int o[4];
    #pragma unroll
    for (int q = 0; q < 4; ++q) {
        float4 f = *(const float4*)(const void*)(p + 4 * q);
        o[q] = (__builtin_amdgcn_cvt_pk_fp8_f32(f.x, f.y, 0, false) & 0xffff)
             | (__builtin_amdgcn_cvt_pk_fp8_f32(f.z, f.w, 0, false) << 16);
    }
    int slot = (nt * 2 + kc) * 64 + lane;
    *(uint4*)(void*)(dst + (size_t)slot * 32 + hf * 16) = make_uint4(o[0], o[1], o[2], o[3]);
}

// ---------------------------------------------------------------------------
// bf16 MFMA GEMM: C[M,N] = act(A[M,K] @ Bw[N,K]^T + bias1 + bias2), bf16 out.
// Block tile 32(M) x 128(N), 4 waves (2x2), each wave 16x64 via 4 accums.
// Row-major C only (the former layout=1 scatter path is gone: it emitted
// 33.5M isolated 2-byte stores, ~64 cache lines touched per wave-store).
// ---------------------------------------------------------------------------
__global__ __launch_bounds__(256) void k_gemm(
    const unsigned short* __restrict__ A, const unsigned short* __restrict__ Bw,
    const int* __restrict__ rowmap,
    const float* __restrict__ bias1, const float* __restrict__ bias2,
    unsigned short* __restrict__ C, int M, int N, int K, int relu)
{
    int tid  = threadIdx.x;
    int lane = tid & 63;
    int wave = tid >> 6;
    int waveM = wave >> 1, waveN = wave & 1;
    int l16  = lane & 15;
    int quad = lane >> 4;
    int mBase = blockIdx.x * 32 + waveM * 16;
    int nBase = blockIdx.y * 128 + waveN * 64;

    int mA = mBase + l16;
    int rowA = rowmap ? rowmap[mA] : mA;
    const unsigned short* pA  = A  + (size_t)rowA * K + quad * 8;
    const unsigned short* pB0 = Bw + (size_t)(nBase +  0 + l16) * K + quad * 8;
    const unsigned short* pB1 = Bw + (size_t)(nBase + 16 + l16) * K + quad * 8;
    const unsigned short* pB2 = Bw + (size_t)(nBase + 32 + l16) * K + quad * 8;
    const unsigned short* pB3 = Bw + (size_t)(nBase + 48 + l16) * K + quad * 8;

    const short8 z8 = {0, 0, 0, 0, 0, 0, 0, 0};
    f32x4 acc0 = {0.f, 0.f, 0.f, 0.f};
    f32x4 acc1 = acc0, acc2 = acc0, acc3 = acc0;

    for (int k0 = 0; k0 < K; k0 += 32) {
        bool ok = (k0 + quad * 8) < K;
        short8 av  = ok ? *(const short8*)(const void*)(pA  + k0) : z8;
        short8 bv0 = ok ? *(const short8*)(const void*)(pB0 + k0) : z8;
        short8 bv1 = ok ? *(const short8*)(const void*)(pB1 + k0) : z8;
        short8 bv2 = ok ? *(const short8*)(const void*)(pB2 + k0) : z8;
        short8 bv3 = ok ? *(const short8*)(const void*)(pB3 + k0) : z8;
        acc0 = __builtin_amdgcn_mfma_f32_16x16x32_bf16(av, bv0, acc0, 0, 0, 0);
        acc1 = __builtin_amdgcn_mfma_f32_16x16x32_bf16(av, bv1, acc1, 0, 0, 0);
        acc2 = __builtin_amdgcn_mfma_f32_16x16x32_bf16(av, bv2, acc2, 0, 0, 0);
        acc3 = __builtin_amdgcn_mfma_f32_16x16x32_bf16(av, bv3, acc3, 0, 0, 0);
    }

    int rowD = mBase + quad * 4;
    #pragma unroll
    for (int nt = 0; nt < 4; ++nt) {
        int col = nBase + nt * 16 + l16;
        float bsum = 0.f;
        if (bias1) bsum += bias1[col];
        if (bias2) bsum += bias2[col];
        f32x4 a = (nt == 0) ? acc0 : (nt == 1) ? acc1 : (nt == 2) ? acc2 : acc3;
        #pragma unroll
        for (int r = 0; r < 4; ++r) {
            float v = a[r] + bsum;
            if (relu) v = v > 0.f ? v : 0.f;
            C[(size_t)(rowD + r) * N + col] = f2bf(v);
        }
    }
}

// ---------------------------------------------------------------------------
// delta features + batch reorder (unchanged)
// ---------------------------------------------------------------------------
__global__ void k_deltas(const unsigned short* __restrict__ hbuf, const int* __restrict__ order,
                         unsigned short* __restrict__ feat)
{
    int bt = blockIdx.x;        // bs*1024 + t
    int c  = threadIdx.x;       // 0..255
    int bs = bt >> 10, t = bt & 1023;
    int b  = order[bs];
    const unsigned short* hb = hbuf + (size_t)b * T_SZ * H3 + c;

    float hv[9];
    #pragma unroll
    for (int d = -4; d <= 4; ++d) {
        int tt = t + d;
        tt = tt < 0 ? 0 : (tt > T_SZ - 1 ? T_SZ - 1 : tt);
        hv[d + 4] = bf2f(hb[(size_t)tt * H3]);
    }
    float d1v[5];
    #pragma unroll
    for (int s = -2; s <= 2; ++s) {
        d1v[s + 2] = (hv[s + 5] - hv[s + 3]) * 0.5f + (hv[s + 6] - hv[s + 2]) * 0.25f;
    }
    int sp1 = (t + 1 > T_SZ - 1 ? T_SZ - 1 : t + 1) - t;
    int sm1 = (t - 1 < 0 ? 0 : t - 1) - t;
    int sp2 = (t + 2 > T_SZ - 1 ? T_SZ - 1 : t + 2) - t;
    int sm2 = (t - 2 < 0 ? 0 : t - 2) - t;
    float d2 = (d1v[2 + sp1] - d1v[2 + sm1]) * 0.5f + (d1v[2 + sp2] - d1v[2 + sm2]) * 0.25f;

    size_t fb = (size_t)bt * FEAT;
    feat[fb + c]       = hb[(size_t)t * H3];
    feat[fb + 256 + c] = f2bf(d1v[2]);
    feat[fb + 512 + c] = f2bf(d2);
}

// ---------------------------------------------------------------------------
// fp8 MX-MFMA LSTM recurrence v6: grid (rq 0..7, dir 0..1) = 16 blocks,
// 4 batch rows/block (batch b at m-row 4b), full Whh register-resident.
// Changes vs v5 (per-step critical path was ~2450 cyc with MFMA pipe busy
// only ~31% of active-CU cycles):
//  - gates are now ROW-MAJOR [row=bs*1024+t][1024]; lane reads 4 dwords
//    (one bf16 pair per gate), register DOUBLE-BUFFERED one full step ahead
//    so the HBM latency never sits on the epilogue's critical path.
//  - adjacent column pairing (col0, col0+1) via permuted k_wfrag8: h-LDS
//    write is one ushort (2 fp8), out store one float2, c0 init one float2.
//  - MFMAs ordered i,f,g then o; c-state VALU overlaps the o-gate MFMAs.
//  - first MFMA of each chain takes a constant-zero accumulator (no 32
//    v_mov zero-inits per step).
// ---------------------------------------------------------------------------
__global__ __launch_bounds__(512, 2) void k_lstm_fp8(
    const unsigned short* __restrict__ g3f, const unsigned short* __restrict__ g3b,
    const unsigned char* __restrict__ wfrag8,
    const float* __restrict__ h0, const float* __restrict__ c0,
    const int* __restrict__ lens_sorted, float* __restrict__ out)
{
    int rq = blockIdx.x, dir = blockIdx.y;
    const unsigned short* g3 = (dir ? g3b : g3f) + (size_t)rq * 4194304;
    const unsigned char* wsrc = wfrag8 + (size_t)dir * 262144;

    __shared__ __align__(16) unsigned char hA[2][4096];

    int tid = threadIdx.x;
    int wave = tid >> 6, lane = tid & 63;
    int l16 = lane & 15, quad = lane >> 4;

    // full Whh resident: 16 x 32B per lane. regB[gb][p][kc]:
    // gb = gate block, p = col parity (cols wave*32+2*l16 / +1), kc = K chunk.
    v8i regB[4][2][2];
    #pragma unroll
    for (int gb = 0; gb < 4; ++gb)
        #pragma unroll
        for (int p = 0; p < 2; ++p)
            #pragma unroll
            for (int kc = 0; kc < 2; ++kc) {
                int nt = gb * 16 + 2 * wave + p;
                regB[gb][p][kc] = *(const v8i*)(const void*)
                    (wsrc + ((size_t)((nt * 2 + kc) * 64 + lane)) * 32);
            }

    // zero both hA buffers (m-rows != 4b stay zero forever; fp8 0x00 == 0.0)
    for (int i = tid; i < 2048; i += 512) ((unsigned int*)(void*)hA)[i] = 0;
    __syncthreads();
    // h0 -> hA[0] at m-row 4b: byte(m,k) at (k>>7)*2048 + (((k>>5)&3)*16+m)*32 + (k&31)
    for (int i = tid; i < 1024; i += 512) {
        int b = i >> 8, c = i & 255;
        float hv = h0[(size_t)dir * B_SZ * HH + (size_t)(rq * 4 + b) * HH + c];
        hA[0][(c >> 7) * 2048 + (((c >> 5) & 3) * 16 + 4 * b) * 32 + (c & 31)] =
            (unsigned char)(__builtin_amdgcn_cvt_pk_fp8_f32(hv, hv, 0, false) & 0xff);
    }

    int grow = rq * 4 + quad;            // this lane's batch row (batch = quad)
    int elen = lens_sorted[grow];
    int maxlen = lens_sorted[rq * 4];    // sorted desc -> first of quad is max
    int col0 = 32 * wave + 2 * l16;      // adjacent pair (col0, col0+1)
    float2 cini = *(const float2*)(const void*)
        (c0 + (size_t)dir * B_SZ * HH + (size_t)grow * HH + col0);
    float c2[2] = {cini.x, cini.y};
    float* out_r = out + (size_t)grow * T_SZ * 512 + dir * HH + col0;
    // gates row-major: addr(shorts) = (grow*1024 + s)*1024 + gb*256 + col0
    const unsigned short* gp = g3 + ((size_t)quad << 20) + col0;
    // LDS write offset for the (col0, col0+1) fp8 pair at m-row 4*quad
    int woff = (col0 >> 7) * 2048 + (((col0 >> 5) & 3) * 16 + 4 * quad) * 32 + (col0 & 31);

    // prefetch step-0 gate inputs (4 dwords: one bf16 pair per gate)
    unsigned int gI = *(const unsigned int*)(const void*)(gp);
    unsigned int gF = *(const unsigned int*)(const void*)(gp + 256);
    unsigned int gG = *(const unsigned int*)(const void*)(gp + 512);
    unsigned int gO = *(const unsigned int*)(const void*)(gp + 768);
    gp += 1024;
    __syncthreads();

    const f32x4 zf = {0.f, 0.f, 0.f, 0.f};
    for (int s = 0; s < maxlen; ++s) {
        // prefetch NEXT step's gates (one full step of MFMA+epilogue to land;
        // last-iteration overread stays inside the workspace and is unused)
        unsigned int nI = *(const unsigned int*)(const void*)(gp);
        unsigned int nF = *(const unsigned int*)(const void*)(gp + 256);
        unsigned int nG = *(const unsigned int*)(const void*)(gp + 512);
        unsigned int nO = *(const unsigned int*)(const void*)(gp + 768);
        gp += 1024;

        // A-fragments: h(s-1), 32B per K-chunk per lane, contiguous
        const unsigned char* Ab = hA[s & 1];
        v8i a0 = *(const v8i*)(const void*)(Ab + lane * 32);
        v8i a1 = *(const v8i*)(const void*)(Ab + 2048 + lane * 32);

        f32x4 acc[4][2];
        // i, f, g gates first ...
        #pragma unroll
        for (int gb = 0; gb < 3; ++gb)
            #pragma unroll
            for (int p = 0; p < 2; ++p) {
                acc[gb][p] = __builtin_amdgcn_mfma_scale_f32_16x16x128_f8f6f4(
                    a0, regB[gb][p][0], zf, 0, 0, 0, 0x7F7F7F7F, 0, 0x7F7F7F7F);
                acc[gb][p] = __builtin_amdgcn_mfma_scale_f32_16x16x128_f8f6f4(
                    a1, regB[gb][p][1], acc[gb][p], 0, 0, 0, 0x7F7F7F7F, 0, 0x7F7F7F7F);
            }
        // ... o gate last, so the c-state VALU below overlaps these 4 MFMAs
        #pragma unroll
        for (int p = 0; p < 2; ++p) {
            acc[3][p] = __builtin_amdgcn_mfma_scale_f32_16x16x128_f8f6f4(
                a0, regB[3][p][0], zf, 0, 0, 0, 0x7F7F7F7F, 0, 0x7F7F7F7F);
            acc[3][p] = __builtin_amdgcn_mfma_scale_f32_16x16x128_f8f6f4(
                a1, regB[3][p][1], acc[3][p], 0, 0, 0, 0x7F7F7F7F, 0, 0x7F7F7F7F);
        }

        // c-state update needs only i,f,g accumulators
        #pragma unroll
        for (int p = 0; p < 2; ++p) {
            float iv = acc[0][p][0] + bf2f((unsigned short)(p ? (gI >> 16) : (gI & 0xffffu)));
            float fv = acc[1][p][0] + bf2f((unsigned short)(p ? (gF >> 16) : (gF & 0xffffu)));
            float gv = acc[2][p][0] + bf2f((unsigned short)(p ? (gG >> 16) : (gG & 0xffffu)));
            c2[p] = sigm(fv) * c2[p] + sigm(iv) * tanh_f(gv);
        }
        float hv0, hv1;
        {
            float ov0 = acc[3][0][0] + bf2f((unsigned short)(gO & 0xffffu));
            float ov1 = acc[3][1][0] + bf2f((unsigned short)(gO >> 16));
            hv0 = sigm(ov0) * tanh_f(c2[0]);
            hv1 = sigm(ov1) * tanh_f(c2[1]);
        }
        // 2 fp8 bytes in one ushort store (cols col0, col0+1 are LDS-adjacent)
        unsigned short pk = (unsigned short)
            (__builtin_amdgcn_cvt_pk_fp8_f32(hv0, hv1, 0, false) & 0xffffu);
        *(unsigned short*)(void*)(hA[(s + 1) & 1] + woff) = pk;
        if (s < elen) {
            int t_out = dir ? (elen - 1 - s) : s;
            *(float2*)(void*)(out_r + (size_t)t_out * 512) = make_float2(hv0, hv1);
        }
        gI = nI; gF = nF; gG = nG; gO = nO;
        __syncthreads();
    }
}

// ---------------------------------------------------------------------------
// Workspace layout (bytes). gates_f overlaps dead a0/a1 regions.
// ---------------------------------------------------------------------------
#define OFF_XBF    ((size_t)0)
#define OFF_A0     ((size_t)5242880)
#define OFF_A1     ((size_t)38797312)
#define OFF_HBUF   ((size_t)72351744)
#define OFF_FEAT   ((size_t)89128960)
#define OFF_GF     OFF_A0                  /* 67,108,864 B over a0+a1 (dead) */
#define OFF_GB     ((size_t)139460608)
#define OFF_W0     ((size_t)206569472)
#define OFF_W1     ((size_t)206651392)
#define OFF_W2     ((size_t)207175680)
#define OFF_WIHF   ((size_t)207437824)
#define OFF_WIHB   ((size_t)209010688)
#define OFF_WFRAG  ((size_t)210583552)     /* 524288 B: fp8 Whh fragments f+b */
#define OFF_ORDER  ((size_t)212680704)
#define OFF_LENS   ((size_t)212680832)
#define OFF_ROWMAP ((size_t)212680960)

extern "C" void kernel_launch(void* const* d_in, const int* in_sizes, int n_in,
                              void* d_out, int out_size, void* d_ws, size_t ws_size,
                              hipStream_t stream)
{
    const float* x    = (const float*)d_in[0];
    const int*   xlen = (const int*)d_in[1];
    const float* eW0  = (const float*)d_in[2];
    const float* eb0  = (const float*)d_in[3];
    const float* eW1  = (const float*)d_in[4];
    const float* eb1  = (const float*)d_in[5];
    const float* eW2  = (const float*)d_in[6];
    const float* eb2  = (const float*)d_in[7];
    const float* Wihf = (const float*)d_in[8];
    const float* Whhf = (const float*)d_in[9];
    const float* bihf = (const float*)d_in[10];
    const float* bhhf = (const float*)d_in[11];
    const float* Wihb = (const float*)d_in[12];
    const float* Whhb = (const float*)d_in[13];
    const float* bihb = (const float*)d_in[14];
    const float* bhhb = (const float*)d_in[15];
    const float* h0   = (const float*)d_in[16];
    const float* c0   = (const float*)d_in[17];
    float* out = (float*)d_out;

    char* ws = (char*)d_ws;
    unsigned short* xbf    = (unsigned short*)(ws + OFF_XBF);
    unsigned short* a0     = (unsigned short*)(ws + OFF_A0);
    unsigned short* a1     = (unsigned short*)(ws + OFF_A1);
    unsigned short* hbuf   = (unsigned short*)(ws + OFF_HBUF);
    unsigned short* feat   = (unsigned short*)(ws + OFF_FEAT);
    unsigned short* gatesF = (unsigned short*)(ws + OFF_GF);
    unsigned short* gatesB = (unsigned short*)(ws + OFF_GB);
    unsigned short* w0     = (unsigned short*)(ws + OFF_W0);
    unsigned short* w1     = (unsigned short*)(ws + OFF_W1);
    unsigned short* w2     = (unsigned short*)(ws + OFF_W2);
    unsigned short* wihf   = (unsigned short*)(ws + OFF_WIHF);
    unsigned short* wihb   = (unsigned short*)(ws + OFF_WIHB);
    unsigned char*  wfrag8 = (unsigned char*)(ws + OFF_WFRAG);
    int* order             = (int*)(ws + OFF_ORDER);
    int* lens_sorted       = (int*)(ws + OFF_LENS);
    int* rowmap            = (int*)(ws + OFF_ROWMAP);

    // prep
    k_cvt<<<2048, 256, 0, stream>>>(x,    xbf,  B_SZ * T_SZ * DIN);
    k_cvt<<<160,  256, 0, stream>>>(eW0,  w0,   512 * 80);
    k_cvt<<<1024, 256, 0, stream>>>(eW1,  w1,   512 * 512);
    k_cvt<<<512,  256, 0, stream>>>(eW2,  w2,   256 * 512);
    k_cvt<<<2048, 256, 0, stream>>>(Wihf, wihf, 1024 * 768);
    k_cvt<<<2048, 256, 0, stream>>>(Wihb, wihb, 1024 * 768);
    k_wfrag8<<<64, 256, 0, stream>>>(Whhf, wfrag8);
    k_wfrag8<<<64, 256, 0, stream>>>(Whhb, wfrag8 + 262144);
    k_order<<<1, 64, 0, stream>>>(xlen, order, lens_sorted, out + (size_t)B_SZ * T_SZ * 512);
    k_rowmap<<<128, 256, 0, stream>>>(lens_sorted, rowmap);
    k_ztail<<<dim3(T_SZ, B_SZ), 128, 0, stream>>>(lens_sorted, out);

    // encoder: 80 -> 512 -> 512 -> 256, ReLU each layer (row-major stores)
    k_gemm<<<dim3(1024, 4), 256, 0, stream>>>(xbf, w0, nullptr, eb0, nullptr, a0,   32768, 512, 80,  1);
    k_gemm<<<dim3(1024, 4), 256, 0, stream>>>(a0,  w1, nullptr, eb1, nullptr, a1,   32768, 512, 512, 1);
    k_gemm<<<dim3(1024, 2), 256, 0, stream>>>(a1,  w2, nullptr, eb2, nullptr, hbuf, 32768, 256, 512, 1);

    // delta features + sort reorder -> feat[bs,t,768]
    k_deltas<<<32768, 256, 0, stream>>>(hbuf, order, feat);

    // gate inputs: feat @ Wih^T + (b_ih + b_hh), ROW-MAJOR [bs*1024+t][1024]
    k_gemm<<<dim3(1024, 8), 256, 0, stream>>>(feat, wihf, nullptr, bihf, bhhf, gatesF, 32768, 1024, 768, 0);
    k_gemm<<<dim3(1024, 8), 256, 0, stream>>>(feat, wihb, rowmap,  bihb, bhhb, gatesB, 32768, 1024, 768, 0);

    // fp8 MX recurrence: 16 independent blocks (2 dirs x 8 batch quads), no sync
    k_lstm_fp8<<<dim3(8, 2), 512, 0, stream>>>(gatesF, gatesB, wfrag8, h0, c0,
                                               lens_sorted, out);
}

// Round 2
// 1244.438 us; speedup vs baseline: 1.9837x; 1.6744x over previous
//
#include <hip/hip_runtime.h>
#include <cstdint>
#include <cstddef>

// ---------------------------------------------------------------------------
// Problem constants
// ---------------------------------------------------------------------------
#define B_SZ 32
#define T_SZ 1024
#define DIN  80
#define H3   256   // encoder output dim
#define FEAT 768   // 3 * H3
#define G4   1024  // 4 * H (LSTM gates)
#define HH   256   // LSTM hidden

typedef __attribute__((ext_vector_type(8))) short short8;   // 8 x bf16 (4 VGPRs)
typedef __attribute__((ext_vector_type(4))) float f32x4;    // MFMA accumulator
typedef __attribute__((ext_vector_type(8))) int v8i;        // 32B fp8 fragment

__device__ inline float bf2f(unsigned short u) {
    return __uint_as_float(((unsigned int)u) << 16);
}
__device__ inline unsigned short f2bf(float f) {
    unsigned int u = __float_as_uint(f);
    u += 0x7fffu + ((u >> 16) & 1u);   // RNE
    return (unsigned short)(u >> 16);
}
// fast sigmoid/tanh: v_exp (exp2) + v_rcp
#define LOG2E 1.4426950408889634f
__device__ inline float sigm(float x) {
    return __builtin_amdgcn_rcpf(1.f + __builtin_amdgcn_exp2f(x * -LOG2E));
}
__device__ inline float tanh_f(float x) {
    return fmaf(2.f, __builtin_amdgcn_rcpf(1.f + __builtin_amdgcn_exp2f(x * (-2.f * LOG2E))), -1.f);
}

// async global->LDS, 16B per lane (dest must be linear: base + lane*16)
__device__ inline void gld16(const void* g, void* l) {
    __builtin_amdgcn_global_load_lds(
        (const __attribute__((address_space(1))) unsigned int*)g,
        (__attribute__((address_space(3))) unsigned int*)l, 16, 0, 0);
}

// ---------------------------------------------------------------------------
// fp32 -> bf16 conversion (grid-stride)
// ---------------------------------------------------------------------------
__global__ void k_cvt(const float* __restrict__ src, unsigned short* __restrict__ dst, int n) {
    int i = blockIdx.x * blockDim.x + threadIdx.x;
    int stride = gridDim.x * blockDim.x;
    for (; i < n; i += stride) dst[i] = f2bf(src[i]);
}

// ---------------------------------------------------------------------------
// stable argsort by descending length (matches jnp.argsort(-lens), stable)
// ---------------------------------------------------------------------------
__global__ void k_order(const int* __restrict__ lens, int* __restrict__ order,
                        int* __restrict__ lens_sorted, float* __restrict__ out_order) {
    int b = threadIdx.x;
    if (b < B_SZ) {
        int lb = lens[b];
        int r = 0;
        for (int j = 0; j < B_SZ; ++j) {
            int lj = lens[j];
            if (lj > lb || (lj == lb && j < b)) ++r;
        }
        order[r] = b;
        lens_sorted[r] = lb;
        out_order[r] = (float)b;   // second tuple output, as float
    }
}

// zero the padded tail: out[bs, t, 0:512] = 0 for t >= len[bs]
__global__ void k_ztail(const int* __restrict__ lens_sorted, float* __restrict__ out) {
    int t = blockIdx.x, bs = blockIdx.y;
    if (t < lens_sorted[bs]) return;
    float4* p = (float4*)(out + ((size_t)bs * T_SZ + t) * 512);
    p[threadIdx.x] = make_float4(0.f, 0.f, 0.f, 0.f);   // 128 threads x 16B
}

// ---------------------------------------------------------------------------
// Whh [1024 rows (n), 256 cols (k)] fp32 -> fp8 e4m3 in MFMA B-fragment order
// for mfma_scale_f32_16x16x128_f8f6f4, with a PERMUTED n-slot assignment so
// that output lane l16 owns ADJACENT gate columns (p=0/1 -> col, col+1):
//   slot (nt, l16): gb = nt>>4, m = nt&15, wave = m>>1, p = m&1
//   gate column n = gb*256 + wave*32 + l16*2 + p
// k mapping unchanged: k = kc*128 + (lane>>4)*32 + j, j = 0..31 contiguous.
// byte addr = ((nt*2 + kc)*64 + lane)*32. One thread per 16-byte half.
// ---------------------------------------------------------------------------
__global__ void k_wfrag8(const float* __restrict__ Whh, unsigned char* __restrict__ dst) {
    int t = blockIdx.x * 256 + threadIdx.x;   // 0..16383
    int lane = t & 63, hf = (t >> 6) & 1, kc = (t >> 7) & 1, nt = t >> 8;
    int l16 = lane & 15;
    int gb = nt >> 4, m = nt & 15, wv = m >> 1, pp = m & 1;
    int n = gb * 256 + wv * 32 + l16 * 2 + pp;     // permuted gate column
    int k0 = kc * 128 + (lane >> 4) * 32 + hf * 16;
    const float* p = Whh + (size_t)n * 256 + k0;
    unsigned int o[4];
    #pragma unroll
    for (int q = 0; q < 4; ++q) {
        float4 f = *(const float4*)(const void*)(p + 4 * q);
        o[q] = (__builtin_amdgcn_cvt_pk_fp8_f32(f.x, f.y, 0, false) & 0xffff)
             | (__builtin_amdgcn_cvt_pk_fp8_f32(f.z, f.w, 0, false) << 16);
    }
    int slot = (nt * 2 + kc) * 64 + lane;
    *(uint4*)(void*)(dst + (size_t)slot * 32 + hf * 16) = make_uint4(o[0], o[1], o[2], o[3]);
}

// ---------------------------------------------------------------------------
// direct bf16 MFMA GEMM (kept only for K=80 encoder layer 0)
// Block tile 32(M) x 128(N), 4 waves (2x2), each wave 16x64 via 4 accums.
// ---------------------------------------------------------------------------
__global__ __launch_bounds__(256) void k_gemm(
    const unsigned short* __restrict__ A, const unsigned short* __restrict__ Bw,
    const float* __restrict__ bias1, const float* __restrict__ bias2,
    unsigned short* __restrict__ C, int M, int N, int K, int relu)
{
    int tid  = threadIdx.x;
    int lane = tid & 63;
    int wave = tid >> 6;
    int waveM = wave >> 1, waveN = wave & 1;
    int l16  = lane & 15;
    int quad = lane >> 4;
    int mBase = blockIdx.x * 32 + waveM * 16;
    int nBase = blockIdx.y * 128 + waveN * 64;

    const unsigned short* pA  = A  + (size_t)(mBase + l16) * K + quad * 8;
    const unsigned short* pB0 = Bw + (size_t)(nBase +  0 + l16) * K + quad * 8;
    const unsigned short* pB1 = Bw + (size_t)(nBase + 16 + l16) * K + quad * 8;
    const unsigned short* pB2 = Bw + (size_t)(nBase + 32 + l16) * K + quad * 8;
    const unsigned short* pB3 = Bw + (size_t)(nBase + 48 + l16) * K + quad * 8;

    const short8 z8 = {0, 0, 0, 0, 0, 0, 0, 0};
    f32x4 acc0 = {0.f, 0.f, 0.f, 0.f};
    f32x4 acc1 = acc0, acc2 = acc0, acc3 = acc0;

    for (int k0 = 0; k0 < K; k0 += 32) {
        bool ok = (k0 + quad * 8) < K;
        short8 av  = ok ? *(const short8*)(const void*)(pA  + k0) : z8;
        short8 bv0 = ok ? *(const short8*)(const void*)(pB0 + k0) : z8;
        short8 bv1 = ok ? *(const short8*)(const void*)(pB1 + k0) : z8;
        short8 bv2 = ok ? *(const short8*)(const void*)(pB2 + k0) : z8;
        short8 bv3 = ok ? *(const short8*)(const void*)(pB3 + k0) : z8;
        acc0 = __builtin_amdgcn_mfma_f32_16x16x32_bf16(av, bv0, acc0, 0, 0, 0);
        acc1 = __builtin_amdgcn_mfma_f32_16x16x32_bf16(av, bv1, acc1, 0, 0, 0);
        acc2 = __builtin_amdgcn_mfma_f32_16x16x32_bf16(av, bv2, acc2, 0, 0, 0);
        acc3 = __builtin_amdgcn_mfma_f32_16x16x32_bf16(av, bv3, acc3, 0, 0, 0);
    }

    int rowD = mBase + quad * 4;
    #pragma unroll
    for (int nt = 0; nt < 4; ++nt) {
        int col = nBase + nt * 16 + l16;
        float bsum = 0.f;
        if (bias1) bsum += bias1[col];
        if (bias2) bsum += bias2[col];
        f32x4 a = (nt == 0) ? acc0 : (nt == 1) ? acc1 : (nt == 2) ? acc2 : acc3;
        #pragma unroll
        for (int r = 0; r < 4; ++r) {
            float v = a[r] + bsum;
            if (relu) v = v > 0.f ? v : 0.f;
            C[(size_t)(rowD + r) * N + col] = f2bf(v);
        }
    }
}

// ---------------------------------------------------------------------------
// LDS-staged bf16 MFMA GEMM (m97 structure: 128x128 tile, BK=32,
// global_load_lds width 16, 2 barriers/K-step). K must be a multiple of 32,
// M and N multiples of 128. grid = (N/128, M/128): x fastest so the 8
// n-blocks sharing one A m-panel dispatch together (A panel L2-hits).
// C[M,N] = act(A[M,K] @ Bw[N,K]^T + bias1 + bias2), bf16 out.
// ---------------------------------------------------------------------------
__global__ __launch_bounds__(256) void k_gemm_t(
    const unsigned short* __restrict__ A, const unsigned short* __restrict__ Bw,
    const float* __restrict__ bias1, const float* __restrict__ bias2,
    unsigned short* __restrict__ C, int N, int K, int relu)
{
    __shared__ unsigned short lA[128 * 32];
    __shared__ unsigned short lB[128 * 32];
    int tid  = threadIdx.x;
    int lane = tid & 63;
    int wave = tid >> 6;
    int l16  = lane & 15, quad = lane >> 4;
    int wm = wave >> 1, wn = wave & 1;
    size_t mBase = (size_t)blockIdx.y * 128;
    size_t nBase = (size_t)blockIdx.x * 128;

    // staging: 512 16B-chunks per matrix / 256 threads = 2 chunks each.
    // chunk c -> LDS bytes [c*16, +16) == row (c>>2), k-part (c&3)*8 shorts.
    int c0 = tid, c1 = tid + 256;
    const unsigned short* sA0 = A  + (mBase + (c0 >> 2)) * K + (c0 & 3) * 8;
    const unsigned short* sA1 = A  + (mBase + (c1 >> 2)) * K + (c1 & 3) * 8;
    const unsigned short* sB0 = Bw + (nBase + (c0 >> 2)) * K + (c0 & 3) * 8;
    const unsigned short* sB1 = Bw + (nBase + (c1 >> 2)) * K + (c1 & 3) * 8;
    unsigned short* dA0 = lA + c0 * 8;
    unsigned short* dA1 = lA + c1 * 8;
    unsigned short* dB0 = lB + c0 * 8;
    unsigned short* dB1 = lB + c1 * 8;

    f32x4 acc[4][4];
    #pragma unroll
    for (int i = 0; i < 4; ++i)
        #pragma unroll
        for (int j = 0; j < 4; ++j) acc[i][j] = (f32x4){0.f, 0.f, 0.f, 0.f};

    const unsigned short* la = lA + (wm * 64 + l16) * 32 + quad * 8;
    const unsigned short* lb = lB + (wn * 64 + l16) * 32 + quad * 8;

    for (int k0 = 0; k0 < K; k0 += 32) {
        gld16(sA0 + k0, dA0);
        gld16(sA1 + k0, dA1);
        gld16(sB0 + k0, dB0);
        gld16(sB1 + k0, dB1);
        __syncthreads();                 // vmcnt(0) drain + barrier: tile ready
        short8 af[4], bf[4];
        #pragma unroll
        for (int i = 0; i < 4; ++i) {
            af[i] = *(const short8*)(const void*)(la + i * 16 * 32);
            bf[i] = *(const short8*)(const void*)(lb + i * 16 * 32);
        }
        #pragma unroll
        for (int i = 0; i < 4; ++i)
            #pragma unroll
            for (int j = 0; j < 4; ++j)
                acc[i][j] = __builtin_amdgcn_mfma_f32_16x16x32_bf16(af[i], bf[j], acc[i][j], 0, 0, 0);
        __syncthreads();                 // frags consumed before next overwrite
    }

    #pragma unroll
    for (int j = 0; j < 4; ++j) {
        int col = (int)nBase + wn * 64 + j * 16 + l16;
        float bsum = 0.f;
        if (bias1) bsum += bias1[col];
        if (bias2) bsum += bias2[col];
        #pragma unroll
        for (int i = 0; i < 4; ++i) {
            int row = (int)mBase + wm * 64 + i * 16 + quad * 4;
            #pragma unroll
            for (int r = 0; r < 4; ++r) {
                float v = acc[i][j][r] + bsum;
                if (relu) v = v > 0.f ? v : 0.f;
                C[(size_t)(row + r) * N + col] = f2bf(v);
            }
        }
    }
}

// ---------------------------------------------------------------------------
// delta features + batch reorder (unchanged)
// ---------------------------------------------------------------------------
__global__ void k_deltas(const unsigned short* __restrict__ hbuf, const int* __restrict__ order,
                         unsigned short* __restrict__ feat)
{
    int bt = blockIdx.x;        // bs*1024 + t
    int c  = threadIdx.x;       // 0..255
    int bs = bt >> 10, t = bt & 1023;
    int b  = order[bs];
    const unsigned short* hb = hbuf + (size_t)b * T_SZ * H3 + c;

    float hv[9];
    #pragma unroll
    for (int d = -4; d <= 4; ++d) {
        int tt = t + d;
        tt = tt < 0 ? 0 : (tt > T_SZ - 1 ? T_SZ - 1 : tt);
        hv[d + 4] = bf2f(hb[(size_t)tt * H3]);
    }
    float d1v[5];
    #pragma unroll
    for (int s = -2; s <= 2; ++s) {
        d1v[s + 2] = (hv[s + 5] - hv[s + 3]) * 0.5f + (hv[s + 6] - hv[s + 2]) * 0.25f;
    }
    int sp1 = (t + 1 > T_SZ - 1 ? T_SZ - 1 : t + 1) - t;
    int sm1 = (t - 1 < 0 ? 0 : t - 1) - t;
    int sp2 = (t + 2 > T_SZ - 1 ? T_SZ - 1 : t + 2) - t;
    int sm2 = (t - 2 < 0 ? 0 : t - 2) - t;
    float d2 = (d1v[2 + sp1] - d1v[2 + sm1]) * 0.5f + (d1v[2 + sp2] - d1v[2 + sm2]) * 0.25f;

    size_t fb = (size_t)bt * FEAT;
    feat[fb + c]       = hb[(size_t)t * H3];
    feat[fb + 256 + c] = f2bf(d1v[2]);
    feat[fb + 512 + c] = f2bf(d2);
}

// ---------------------------------------------------------------------------
// fp8 MX-MFMA LSTM recurrence v7: grid (rq 0..7, dir 0..1) = 16 blocks,
// 4 batch rows/block (batch b at m-row 4b), full Whh register-resident.
// Changes vs v6:
//  - per-step barrier is now raw s_barrier with only lgkmcnt(0) before it
//    (the h LDS write). __syncthreads() drained vmcnt(0) too, putting the
//    out-store write-ack AND gate prefetch on the per-step critical path.
//  - backward direction reads UNREVERSED row-major gates at
//    row = clamp(elen-1-s, 0, 1023) (matches reference's clipped x_rev;
//    padding steps' h never reaches the stored output). This removes the
//    rowmap'd A-gather from the backward gates GEMM.
// ---------------------------------------------------------------------------
__global__ __launch_bounds__(512, 2) void k_lstm_fp8(
    const unsigned short* __restrict__ g3f, const unsigned short* __restrict__ g3b,
    const unsigned char* __restrict__ wfrag8,
    const float* __restrict__ h0, const float* __restrict__ c0,
    const int* __restrict__ lens_sorted, float* __restrict__ out)
{
    int rq = blockIdx.x, dir = blockIdx.y;
    const unsigned short* g3 = (dir ? g3b : g3f) + (size_t)rq * 4194304;
    const unsigned char* wsrc = wfrag8 + (size_t)dir * 262144;

    __shared__ __align__(16) unsigned char hA[2][4096];

    int tid = threadIdx.x;
    int wave = tid >> 6, lane = tid & 63;
    int l16 = lane & 15, quad = lane >> 4;

    // full Whh resident: 16 x 32B per lane. regB[gb][p][kc]:
    // gb = gate block, p = col parity (cols wave*32+2*l16 / +1), kc = K chunk.
    v8i regB[4][2][2];
    #pragma unroll
    for (int gb = 0; gb < 4; ++gb)
        #pragma unroll
        for (int p = 0; p < 2; ++p)
            #pragma unroll
            for (int kc = 0; kc < 2; ++kc) {
                int nt = gb * 16 + 2 * wave + p;
                regB[gb][p][kc] = *(const v8i*)(const void*)
                    (wsrc + ((size_t)((nt * 2 + kc) * 64 + lane)) * 32);
            }

    // zero both hA buffers (m-rows != 4b stay zero forever; fp8 0x00 == 0.0)
    for (int i = tid; i < 2048; i += 512) ((unsigned int*)(void*)hA)[i] = 0;
    __syncthreads();
    // h0 -> hA[0] at m-row 4b: byte(m,k) at (k>>7)*2048 + (((k>>5)&3)*16+m)*32 + (k&31)
    for (int i = tid; i < 1024; i += 512) {
        int b = i >> 8, c = i & 255;
        float hv = h0[(size_t)dir * B_SZ * HH + (size_t)(rq * 4 + b) * HH + c];
        hA[0][(c >> 7) * 2048 + (((c >> 5) & 3) * 16 + 4 * b) * 32 + (c & 31)] =
            (unsigned char)(__builtin_amdgcn_cvt_pk_fp8_f32(hv, hv, 0, false) & 0xff);
    }

    int grow = rq * 4 + quad;            // this lane's batch row (batch = quad)
    int elen = lens_sorted[grow];
    int maxlen = lens_sorted[rq * 4];    // sorted desc -> first of quad is max
    int col0 = 32 * wave + 2 * l16;      // adjacent pair (col0, col0+1)
    float2 cini = *(const float2*)(const void*)
        (c0 + (size_t)dir * B_SZ * HH + (size_t)grow * HH + col0);
    float c2[2] = {cini.x, cini.y};
    float* out_r = out + (size_t)grow * T_SZ * 512 + dir * HH + col0;
    // gates row-major: row base for batch grow, this lane's column pair
    const unsigned short* gbase0 = g3 + ((size_t)quad << 20) + col0;
    // LDS write offset for the (col0, col0+1) fp8 pair at m-row 4*quad
    int woff = (col0 >> 7) * 2048 + (((col0 >> 5) & 3) * 16 + 4 * quad) * 32 + (col0 & 31);

    // gate row for step s: forward s, backward clamp(elen-1-s, 0, 1023)
    auto growp = [&](int s) -> const unsigned short* {
        int tr = dir ? (elen - 1 - s) : s;
        tr = tr < 0 ? 0 : (tr > T_SZ - 1 ? T_SZ - 1 : tr);
        return gbase0 + ((size_t)tr << 10);
    };

    // prefetch step-0 gate inputs (4 dwords: one bf16 pair per gate)
    const unsigned short* rp = growp(0);
    unsigned int gI = *(const unsigned int*)(const void*)(rp);
    unsigned int gF = *(const unsigned int*)(const void*)(rp + 256);
    unsigned int gG = *(const unsigned int*)(const void*)(rp + 512);
    unsigned int gO = *(const unsigned int*)(const void*)(rp + 768);
    __syncthreads();

    const f32x4 zf = {0.f, 0.f, 0.f, 0.f};
    for (int s = 0; s < maxlen; ++s) {
        // prefetch NEXT step's gates (a full step of MFMA+epilogue to land)
        const unsigned short* rn = growp(s + 1);
        unsigned int nI = *(const unsigned int*)(const void*)(rn);
        unsigned int nF = *(const unsigned int*)(const void*)(rn + 256);
        unsigned int nG = *(const unsigned int*)(const void*)(rn + 512);
        unsigned int nO = *(const unsigned int*)(const void*)(rn + 768);

        // A-fragments: h(s-1), 32B per K-chunk per lane, contiguous
        const unsigned char* Ab = hA[s & 1];
        v8i a0 = *(const v8i*)(const void*)(Ab + lane * 32);
        v8i a1 = *(const v8i*)(const void*)(Ab + 2048 + lane * 32);

        f32x4 acc[4][2];
        // i, f, g gates first ...
        #pragma unroll
        for (int gb = 0; gb < 3; ++gb)
            #pragma unroll
            for (int p = 0; p < 2; ++p) {
                acc[gb][p] = __builtin_amdgcn_mfma_scale_f32_16x16x128_f8f6f4(
                    a0, regB[gb][p][0], zf, 0, 0, 0, 0x7F7F7F7F, 0, 0x7F7F7F7F);
                acc[gb][p] = __builtin_amdgcn_mfma_scale_f32_16x16x128_f8f6f4(
                    a1, regB[gb][p][1], acc[gb][p], 0, 0, 0, 0x7F7F7F7F, 0, 0x7F7F7F7F);
            }
        // ... o gate last, so the c-state VALU below overlaps these 4 MFMAs
        #pragma unroll
        for (int p = 0; p < 2; ++p) {
            acc[3][p] = __builtin_amdgcn_mfma_scale_f32_16x16x128_f8f6f4(
                a0, regB[3][p][0], zf, 0, 0, 0, 0x7F7F7F7F, 0, 0x7F7F7F7F);
            acc[3][p] = __builtin_amdgcn_mfma_scale_f32_16x16x128_f8f6f4(
                a1, regB[3][p][1], acc[3][p], 0, 0, 0, 0x7F7F7F7F, 0, 0x7F7F7F7F);
        }

        // c-state update needs only i,f,g accumulators
        #pragma unroll
        for (int p = 0; p < 2; ++p) {
            float iv = acc[0][p][0] + bf2f((unsigned short)(p ? (gI >> 16) : (gI & 0xffffu)));
            float fv = acc[1][p][0] + bf2f((unsigned short)(p ? (gF >> 16) : (gF & 0xffffu)));
            float gv = acc[2][p][0] + bf2f((unsigned short)(p ? (gG >> 16) : (gG & 0xffffu)));
            c2[p] = sigm(fv) * c2[p] + sigm(iv) * tanh_f(gv);
        }
        float hv0, hv1;
        {
            float ov0 = acc[3][0][0] + bf2f((unsigned short)(gO & 0xffffu));
            float ov1 = acc[3][1][0] + bf2f((unsigned short)(gO >> 16));
            hv0 = sigm(ov0) * tanh_f(c2[0]);
            hv1 = sigm(ov1) * tanh_f(c2[1]);
        }
        // 2 fp8 bytes in one ushort store (cols col0, col0+1 are LDS-adjacent)
        unsigned short pk = (unsigned short)
            (__builtin_amdgcn_cvt_pk_fp8_f32(hv0, hv1, 0, false) & 0xffffu);
        *(unsigned short*)(void*)(hA[(s + 1) & 1] + woff) = pk;
        if (s < elen) {
            int t_out = dir ? (elen - 1 - s) : s;
            *(float2*)(void*)(out_r + (size_t)t_out * 512) = make_float2(hv0, hv1);
        }
        gI = nI; gF = nF; gG = nG; gO = nO;
        // raw barrier: only the LDS h-write must drain; the out-store and
        // next-step gate loads stay in flight across the barrier.
        asm volatile("s_waitcnt lgkmcnt(0)" ::: "memory");
        __builtin_amdgcn_s_barrier();
    }
}

// ---------------------------------------------------------------------------
// Workspace layout (bytes). gates_f overlaps dead a0/a1 regions.
// ---------------------------------------------------------------------------
#define OFF_XBF    ((size_t)0)
#define OFF_A0     ((size_t)5242880)
#define OFF_A1     ((size_t)38797312)
#define OFF_HBUF   ((size_t)72351744)
#define OFF_FEAT   ((size_t)89128960)
#define OFF_GF     OFF_A0                  /* 67,108,864 B over a0+a1 (dead) */
#define OFF_GB     ((size_t)139460608)
#define OFF_W0     ((size_t)206569472)
#define OFF_W1     ((size_t)206651392)
#define OFF_W2     ((size_t)207175680)
#define OFF_WIHF   ((size_t)207437824)
#define OFF_WIHB   ((size_t)209010688)
#define OFF_WFRAG  ((size_t)210583552)     /* 524288 B: fp8 Whh fragments f+b */
#define OFF_ORDER  ((size_t)212680704)
#define OFF_LENS   ((size_t)212680832)

extern "C" void kernel_launch(void* const* d_in, const int* in_sizes, int n_in,
                              void* d_out, int out_size, void* d_ws, size_t ws_size,
                              hipStream_t stream)
{
    const float* x    = (const float*)d_in[0];
    const int*   xlen = (const int*)d_in[1];
    const float* eW0  = (const float*)d_in[2];
    const float* eb0  = (const float*)d_in[3];
    const float* eW1  = (const float*)d_in[4];
    const float* eb1  = (const float*)d_in[5];
    const float* eW2  = (const float*)d_in[6];
    const float* eb2  = (const float*)d_in[7];
    const float* Wihf = (const float*)d_in[8];
    const float* Whhf = (const float*)d_in[9];
    const float* bihf = (const float*)d_in[10];
    const float* bhhf = (const float*)d_in[11];
    const float* Wihb = (const float*)d_in[12];
    const float* Whhb = (const float*)d_in[13];
    const float* bihb = (const float*)d_in[14];
    const float* bhhb = (const float*)d_in[15];
    const float* h0   = (const float*)d_in[16];
    const float* c0   = (const float*)d_in[17];
    float* out = (float*)d_out;

    char* ws = (char*)d_ws;
    unsigned short* xbf    = (unsigned short*)(ws + OFF_XBF);
    unsigned short* a0     = (unsigned short*)(ws + OFF_A0);
    unsigned short* a1     = (unsigned short*)(ws + OFF_A1);
    unsigned short* hbuf   = (unsigned short*)(ws + OFF_HBUF);
    unsigned short* feat   = (unsigned short*)(ws + OFF_FEAT);
    unsigned short* gatesF = (unsigned short*)(ws + OFF_GF);
    unsigned short* gatesB = (unsigned short*)(ws + OFF_GB);
    unsigned short* w0     = (unsigned short*)(ws + OFF_W0);
    unsigned short* w1     = (unsigned short*)(ws + OFF_W1);
    unsigned short* w2     = (unsigned short*)(ws + OFF_W2);
    unsigned short* wihf   = (unsigned short*)(ws + OFF_WIHF);
    unsigned short* wihb   = (unsigned short*)(ws + OFF_WIHB);
    unsigned char*  wfrag8 = (unsigned char*)(ws + OFF_WFRAG);
    int* order             = (int*)(ws + OFF_ORDER);
    int* lens_sorted       = (int*)(ws + OFF_LENS);

    // prep
    k_cvt<<<2048, 256, 0, stream>>>(x,    xbf,  B_SZ * T_SZ * DIN);
    k_cvt<<<160,  256, 0, stream>>>(eW0,  w0,   512 * 80);
    k_cvt<<<1024, 256, 0, stream>>>(eW1,  w1,   512 * 512);
    k_cvt<<<512,  256, 0, stream>>>(eW2,  w2,   256 * 512);
    k_cvt<<<2048, 256, 0, stream>>>(Wihf, wihf, 1024 * 768);
    k_cvt<<<2048, 256, 0, stream>>>(Wihb, wihb, 1024 * 768);
    k_wfrag8<<<64, 256, 0, stream>>>(Whhf, wfrag8);
    k_wfrag8<<<64, 256, 0, stream>>>(Whhb, wfrag8 + 262144);
    k_order<<<1, 64, 0, stream>>>(xlen, order, lens_sorted, out + (size_t)B_SZ * T_SZ * 512);
    k_ztail<<<dim3(T_SZ, B_SZ), 128, 0, stream>>>(lens_sorted, out);

    // encoder: 80 -> 512 -> 512 -> 256, ReLU each layer (row-major stores)
    k_gemm<<<dim3(1024, 4), 256, 0, stream>>>(xbf, w0, nullptr, eb0, a0, 32768, 512, 80, 1);
    k_gemm_t<<<dim3(4, 256), 256, 0, stream>>>(a0, w1, eb1, nullptr, a1,   512, 512, 1);
    k_gemm_t<<<dim3(2, 256), 256, 0, stream>>>(a1, w2, eb2, nullptr, hbuf, 256, 512, 1);

    // delta features + sort reorder -> feat[bs,t,768]
    k_deltas<<<32768, 256, 0, stream>>>(hbuf, order, feat);

    // gate inputs: feat @ Wih^T + (b_ih + b_hh), ROW-MAJOR [bs*1024+t][1024]
    // (both directions unreversed; backward reversal happens in the LSTM reads)
    k_gemm_t<<<dim3(8, 256), 256, 0, stream>>>(feat, wihf, bihf, bhhf, gatesF, 1024, 768, 0);
    k_gemm_t<<<dim3(8, 256), 256, 0, stream>>>(feat, wihb, bihb, bhhb, gatesB, 1024, 768, 0);

    // fp8 MX recurrence: 16 independent blocks (2 dirs x 8 batch quads), no sync
    k_lstm_fp8<<<dim3(8, 2), 512, 0, stream>>>(gatesF, gatesB, wfrag8, h0, c0,
                                               lens_sorted, out);
}

// Round 3
// 1236.105 us; speedup vs baseline: 1.9971x; 1.0067x over previous
//
#include <hip/hip_runtime.h>
#include <cstdint>
#include <cstddef>

// ---------------------------------------------------------------------------
// Problem constants
// ---------------------------------------------------------------------------
#define B_SZ 32
#define T_SZ 1024
#define DIN  80
#define H3   256   // encoder output dim
#define FEAT 768   // 3 * H3
#define G4   1024  // 4 * H (LSTM gates)
#define HH   256   // LSTM hidden

typedef __attribute__((ext_vector_type(8))) short short8;   // 8 x bf16 (4 VGPRs)
typedef __attribute__((ext_vector_type(4))) float f32x4;    // MFMA accumulator
typedef __attribute__((ext_vector_type(8))) int v8i;        // 32B fp8 fragment

__device__ inline float bf2f(unsigned short u) {
    return __uint_as_float(((unsigned int)u) << 16);
}
__device__ inline unsigned short f2bf(float f) {
    unsigned int u = __float_as_uint(f);
    u += 0x7fffu + ((u >> 16) & 1u);   // RNE
    return (unsigned short)(u >> 16);
}
// fast sigmoid/tanh: v_exp (exp2) + v_rcp
#define LOG2E 1.4426950408889634f
__device__ inline float sigm(float x) {
    return __builtin_amdgcn_rcpf(1.f + __builtin_amdgcn_exp2f(x * -LOG2E));
}
__device__ inline float tanh_f(float x) {
    return fmaf(2.f, __builtin_amdgcn_rcpf(1.f + __builtin_amdgcn_exp2f(x * (-2.f * LOG2E))), -1.f);
}

// async global->LDS, 16B per lane (dest must be linear: base + lane*16)
__device__ inline void gld16(const void* g, void* l) {
    __builtin_amdgcn_global_load_lds(
        (const __attribute__((address_space(1))) unsigned int*)g,
        (__attribute__((address_space(3))) unsigned int*)l, 16, 0, 0);
}

// ---------------------------------------------------------------------------
// fp32 -> bf16 conversion, float4-vectorized (n4 = n/4)
// ---------------------------------------------------------------------------
__device__ inline void cvt_seg(const float* __restrict__ s, unsigned short* __restrict__ d,
                               int n4, int i, int stride) {
    for (int k = i; k < n4; k += stride) {
        float4 f = ((const float4*)(const void*)s)[k];
        ushort4 u;
        u.x = f2bf(f.x); u.y = f2bf(f.y); u.z = f2bf(f.z); u.w = f2bf(f.w);
        ((ushort4*)(void*)d)[k] = u;
    }
}

__global__ void k_cvt4(const float* __restrict__ src, unsigned short* __restrict__ dst, int n4) {
    int i = blockIdx.x * 256 + threadIdx.x;
    cvt_seg(src, dst, n4, i, gridDim.x * 256);
}

// all five weight matrices in one launch (saves 4 kernel-launch overheads)
__global__ void k_cvtw(const float* __restrict__ s0, unsigned short* __restrict__ d0,
                       const float* __restrict__ s1, unsigned short* __restrict__ d1,
                       const float* __restrict__ s2, unsigned short* __restrict__ d2,
                       const float* __restrict__ s3, unsigned short* __restrict__ d3,
                       const float* __restrict__ s4, unsigned short* __restrict__ d4) {
    int i = blockIdx.x * 256 + threadIdx.x;
    int stride = gridDim.x * 256;
    cvt_seg(s0, d0, 10240,  i, stride);   // 512*80
    cvt_seg(s1, d1, 65536,  i, stride);   // 512*512
    cvt_seg(s2, d2, 32768,  i, stride);   // 256*512
    cvt_seg(s3, d3, 196608, i, stride);   // 1024*768
    cvt_seg(s4, d4, 196608, i, stride);   // 1024*768
}

// ---------------------------------------------------------------------------
// stable argsort by descending length (matches jnp.argsort(-lens), stable)
// ---------------------------------------------------------------------------
__global__ void k_order(const int* __restrict__ lens, int* __restrict__ order,
                        int* __restrict__ lens_sorted, float* __restrict__ out_order) {
    int b = threadIdx.x;
    if (b < B_SZ) {
        int lb = lens[b];
        int r = 0;
        for (int j = 0; j < B_SZ; ++j) {
            int lj = lens[j];
            if (lj > lb || (lj == lb && j < b)) ++r;
        }
        order[r] = b;
        lens_sorted[r] = lb;
        out_order[r] = (float)b;   // second tuple output, as float
    }
}

// zero the padded tail: out[bs, t, 0:512] = 0 for t >= len[bs]
__global__ void k_ztail(const int* __restrict__ lens_sorted, float* __restrict__ out) {
    int t = blockIdx.x, bs = blockIdx.y;
    if (t < lens_sorted[bs]) return;
    float4* p = (float4*)(out + ((size_t)bs * T_SZ + t) * 512);
    p[threadIdx.x] = make_float4(0.f, 0.f, 0.f, 0.f);   // 128 threads x 16B
}

// ---------------------------------------------------------------------------
// Whh [1024 rows (n), 256 cols (k)] fp32 -> fp8 e4m3 in MFMA B-fragment order
// for mfma_scale_f32_16x16x128_f8f6f4, with a PERMUTED n-slot assignment so
// that output lane l16 owns ADJACENT gate columns (p=0/1 -> col, col+1):
//   slot (nt, l16): gb = nt>>4, m = nt&15, wave = m>>1, p = m&1
//   gate column n = gb*256 + wave*32 + l16*2 + p
// k mapping unchanged: k = kc*128 + (lane>>4)*32 + j, j = 0..31 contiguous.
// byte addr = ((nt*2 + kc)*64 + lane)*32. One thread per 16-byte half.
// Both directions in one launch: grid 128, dir = blockIdx.x >= 64.
// ---------------------------------------------------------------------------
__global__ void k_wfrag8(const float* __restrict__ Whhf, const float* __restrict__ Whhb,
                         unsigned char* __restrict__ dst) {
    int t = blockIdx.x * 256 + threadIdx.x;   // 0..32767
    int dir = t >> 14;
    t &= 16383;
    const float* Whh = dir ? Whhb : Whhf;
    unsigned char* d = dst + (size_t)dir * 262144;
    int lane = t & 63, hf = (t >> 6) & 1, kc = (t >> 7) & 1, nt = t >> 8;
    int l16 = lane & 15;
    int gb = nt >> 4, m = nt & 15, wv = m >> 1, pp = m & 1;
    int n = gb * 256 + wv * 32 + l16 * 2 + pp;     // permuted gate column
    int k0 = kc * 128 + (lane >> 4) * 32 + hf * 16;
    const float* p = Whh + (size_t)n * 256 + k0;
    unsigned int o[4];
    #pragma unroll
    for (int q = 0; q < 4; ++q) {
        float4 f = *(const float4*)(const void*)(p + 4 * q);
        o[q] = (__builtin_amdgcn_cvt_pk_fp8_f32(f.x, f.y, 0, false) & 0xffff)
             | (__builtin_amdgcn_cvt_pk_fp8_f32(f.z, f.w, 0, false) << 16);
    }
    int slot = (nt * 2 + kc) * 64 + lane;
    *(uint4*)(void*)(d + (size_t)slot * 32 + hf * 16) = make_uint4(o[0], o[1], o[2], o[3]);
}

// ---------------------------------------------------------------------------
// direct bf16 MFMA GEMM (kept only for K=80 encoder layer 0)
// Block tile 32(M) x 128(N), 4 waves (2x2), each wave 16x64 via 4 accums.
// ---------------------------------------------------------------------------
__global__ __launch_bounds__(256) void k_gemm(
    const unsigned short* __restrict__ A, const unsigned short* __restrict__ Bw,
    const float* __restrict__ bias1, const float* __restrict__ bias2,
    unsigned short* __restrict__ C, int M, int N, int K, int relu)
{
    int tid  = threadIdx.x;
    int lane = tid & 63;
    int wave = tid >> 6;
    int waveM = wave >> 1, waveN = wave & 1;
    int l16  = lane & 15;
    int quad = lane >> 4;
    int mBase = blockIdx.x * 32 + waveM * 16;
    int nBase = blockIdx.y * 128 + waveN * 64;

    const unsigned short* pA  = A  + (size_t)(mBase + l16) * K + quad * 8;
    const unsigned short* pB0 = Bw + (size_t)(nBase +  0 + l16) * K + quad * 8;
    const unsigned short* pB1 = Bw + (size_t)(nBase + 16 + l16) * K + quad * 8;
    const unsigned short* pB2 = Bw + (size_t)(nBase + 32 + l16) * K + quad * 8;
    const unsigned short* pB3 = Bw + (size_t)(nBase + 48 + l16) * K + quad * 8;

    const short8 z8 = {0, 0, 0, 0, 0, 0, 0, 0};
    f32x4 acc0 = {0.f, 0.f, 0.f, 0.f};
    f32x4 acc1 = acc0, acc2 = acc0, acc3 = acc0;

    for (int k0 = 0; k0 < K; k0 += 32) {
        bool ok = (k0 + quad * 8) < K;
        short8 av  = ok ? *(const short8*)(const void*)(pA  + k0) : z8;
        short8 bv0 = ok ? *(const short8*)(const void*)(pB0 + k0) : z8;
        short8 bv1 = ok ? *(const short8*)(const void*)(pB1 + k0) : z8;
        short8 bv2 = ok ? *(const short8*)(const void*)(pB2 + k0) : z8;
        short8 bv3 = ok ? *(const short8*)(const void*)(pB3 + k0) : z8;
        acc0 = __builtin_amdgcn_mfma_f32_16x16x32_bf16(av, bv0, acc0, 0, 0, 0);
        acc1 = __builtin_amdgcn_mfma_f32_16x16x32_bf16(av, bv1, acc1, 0, 0, 0);
        acc2 = __builtin_amdgcn_mfma_f32_16x16x32_bf16(av, bv2, acc2, 0, 0, 0);
        acc3 = __builtin_amdgcn_mfma_f32_16x16x32_bf16(av, bv3, acc3, 0, 0, 0);
    }

    int rowD = mBase + quad * 4;
    #pragma unroll
    for (int nt = 0; nt < 4; ++nt) {
        int col = nBase + nt * 16 + l16;
        float bsum = 0.f;
        if (bias1) bsum += bias1[col];
        if (bias2) bsum += bias2[col];
        f32x4 a = (nt == 0) ? acc0 : (nt == 1) ? acc1 : (nt == 2) ? acc2 : acc3;
        #pragma unroll
        for (int r = 0; r < 4; ++r) {
            float v = a[r] + bsum;
            if (relu) v = v > 0.f ? v : 0.f;
            C[(size_t)(rowD + r) * N + col] = f2bf(v);
        }
    }
}

// ---------------------------------------------------------------------------
// LDS-staged bf16 MFMA GEMM (m97 structure: 128x128 tile, BK=32,
// global_load_lds width 16, 2 barriers/K-step). K multiple of 32,
// M and N multiples of 128. grid = (N/128, M/128).
// C[M,N] = act(A[M,K] @ Bw[N,K]^T + bias1 + bias2), bf16 out.
// ---------------------------------------------------------------------------
__global__ __launch_bounds__(256) void k_gemm_t(
    const unsigned short* __restrict__ A, const unsigned short* __restrict__ Bw,
    const float* __restrict__ bias1, const float* __restrict__ bias2,
    unsigned short* __restrict__ C, int N, int K, int relu)
{
    __shared__ unsigned short lA[128 * 32];
    __shared__ unsigned short lB[128 * 32];
    int tid  = threadIdx.x;
    int lane = tid & 63;
    int wave = tid >> 6;
    int l16  = lane & 15, quad = lane >> 4;
    int wm = wave >> 1, wn = wave & 1;
    size_t mBase = (size_t)blockIdx.y * 128;
    size_t nBase = (size_t)blockIdx.x * 128;

    int c0 = tid, c1 = tid + 256;
    const unsigned short* sA0 = A  + (mBase + (c0 >> 2)) * K + (c0 & 3) * 8;
    const unsigned short* sA1 = A  + (mBase + (c1 >> 2)) * K + (c1 & 3) * 8;
    const unsigned short* sB0 = Bw + (nBase + (c0 >> 2)) * K + (c0 & 3) * 8;
    const unsigned short* sB1 = Bw + (nBase + (c1 >> 2)) * K + (c1 & 3) * 8;
    unsigned short* dA0 = lA + c0 * 8;
    unsigned short* dA1 = lA + c1 * 8;
    unsigned short* dB0 = lB + c0 * 8;
    unsigned short* dB1 = lB + c1 * 8;

    f32x4 acc[4][4];
    #pragma unroll
    for (int i = 0; i < 4; ++i)
        #pragma unroll
        for (int j = 0; j < 4; ++j) acc[i][j] = (f32x4){0.f, 0.f, 0.f, 0.f};

    const unsigned short* la = lA + (wm * 64 + l16) * 32 + quad * 8;
    const unsigned short* lb = lB + (wn * 64 + l16) * 32 + quad * 8;

    for (int k0 = 0; k0 < K; k0 += 32) {
        gld16(sA0 + k0, dA0);
        gld16(sA1 + k0, dA1);
        gld16(sB0 + k0, dB0);
        gld16(sB1 + k0, dB1);
        __syncthreads();                 // vmcnt(0) drain + barrier: tile ready
        short8 af[4], bf[4];
        #pragma unroll
        for (int i = 0; i < 4; ++i) {
            af[i] = *(const short8*)(const void*)(la + i * 16 * 32);
            bf[i] = *(const short8*)(const void*)(lb + i * 16 * 32);
        }
        #pragma unroll
        for (int i = 0; i < 4; ++i)
            #pragma unroll
            for (int j = 0; j < 4; ++j)
                acc[i][j] = __builtin_amdgcn_mfma_f32_16x16x32_bf16(af[i], bf[j], acc[i][j], 0, 0, 0);
        __syncthreads();                 // frags consumed before next overwrite
    }

    #pragma unroll
    for (int j = 0; j < 4; ++j) {
        int col = (int)nBase + wn * 64 + j * 16 + l16;
        float bsum = 0.f;
        if (bias1) bsum += bias1[col];
        if (bias2) bsum += bias2[col];
        #pragma unroll
        for (int i = 0; i < 4; ++i) {
            int row = (int)mBase + wm * 64 + i * 16 + quad * 4;
            #pragma unroll
            for (int r = 0; r < 4; ++r) {
                float v = acc[i][j][r] + bsum;
                if (relu) v = v > 0.f ? v : 0.f;
                C[(size_t)(row + r) * N + col] = f2bf(v);
            }
        }
    }
}

// ---------------------------------------------------------------------------
// delta features + batch reorder (unchanged)
// ---------------------------------------------------------------------------
__global__ void k_deltas(const unsigned short* __restrict__ hbuf, const int* __restrict__ order,
                         unsigned short* __restrict__ feat)
{
    int bt = blockIdx.x;        // bs*1024 + t
    int c  = threadIdx.x;       // 0..255
    int bs = bt >> 10, t = bt & 1023;
    int b  = order[bs];
    const unsigned short* hb = hbuf + (size_t)b * T_SZ * H3 + c;

    float hv[9];
    #pragma unroll
    for (int d = -4; d <= 4; ++d) {
        int tt = t + d;
        tt = tt < 0 ? 0 : (tt > T_SZ - 1 ? T_SZ - 1 : tt);
        hv[d + 4] = bf2f(hb[(size_t)tt * H3]);
    }
    float d1v[5];
    #pragma unroll
    for (int s = -2; s <= 2; ++s) {
        d1v[s + 2] = (hv[s + 5] - hv[s + 3]) * 0.5f + (hv[s + 6] - hv[s + 2]) * 0.25f;
    }
    int sp1 = (t + 1 > T_SZ - 1 ? T_SZ - 1 : t + 1) - t;
    int sm1 = (t - 1 < 0 ? 0 : t - 1) - t;
    int sp2 = (t + 2 > T_SZ - 1 ? T_SZ - 1 : t + 2) - t;
    int sm2 = (t - 2 < 0 ? 0 : t - 2) - t;
    float d2 = (d1v[2 + sp1] - d1v[2 + sm1]) * 0.5f + (d1v[2 + sp2] - d1v[2 + sm2]) * 0.25f;

    size_t fb = (size_t)bt * FEAT;
    feat[fb + c]       = hb[(size_t)t * H3];
    feat[fb + 256 + c] = f2bf(d1v[2]);
    feat[fb + 512 + c] = f2bf(d2);
}

// ---------------------------------------------------------------------------
// fp8 MX-MFMA LSTM recurrence v8: grid (rq 0..7, dir 0..1) = 16 blocks,
// 4 batch rows/block (batch b at m-row 4b), full Whh register-resident.
// Changes vs v7 (step time stuck at ~1930 cyc, MFMA floor 1104):
//  - PHASE-SPLIT MFMA issue: all 8 independent kc=0 MFMAs first, then all
//    8 kc=1. v7 emitted each chain's two MFMAs adjacently, so in-order
//    wave issue stalled on the ~50-cyc MFMA result latency between every
//    pair instead of issuing the 7 other independent chains.
//  - tanh(c2) hoisted above the o-accumulator read (depends only on i,f,g)
//    -> shortens the post-MFMA serial tail by one transcendental chain.
//  - gate prefetch: one pointer + 3 immediate-offset loads (512/1024/1536B
//    fit the 13-bit signed global offset); per-step address math is one
//    clamped shift-add instead of the v7 lambda's 4 x 64-bit chains.
//  - ds_read of A-fragments issued FIRST after the barrier.
// ---------------------------------------------------------------------------
__global__ __launch_bounds__(512, 2) void k_lstm_fp8(
    const unsigned short* __restrict__ g3f, const unsigned short* __restrict__ g3b,
    const unsigned char* __restrict__ wfrag8,
    const float* __restrict__ h0, const float* __restrict__ c0,
    const int* __restrict__ lens_sorted, float* __restrict__ out)
{
    int rq = blockIdx.x, dir = blockIdx.y;
    const unsigned short* g3 = (dir ? g3b : g3f) + (size_t)rq * 4194304;
    const unsigned char* wsrc = wfrag8 + (size_t)dir * 262144;

    __shared__ __align__(16) unsigned char hA[2][4096];

    int tid = threadIdx.x;
    int wave = tid >> 6, lane = tid & 63;
    int l16 = lane & 15, quad = lane >> 4;

    // full Whh resident: 16 x 32B per lane. regB[gb][p][kc]:
    // gb = gate block, p = col parity (cols wave*32+2*l16 / +1), kc = K chunk.
    v8i regB[4][2][2];
    #pragma unroll
    for (int gb = 0; gb < 4; ++gb)
        #pragma unroll
        for (int p = 0; p < 2; ++p)
            #pragma unroll
            for (int kc = 0; kc < 2; ++kc) {
                int nt = gb * 16 + 2 * wave + p;
                regB[gb][p][kc] = *(const v8i*)(const void*)
                    (wsrc + ((size_t)((nt * 2 + kc) * 64 + lane)) * 32);
            }

    // zero both hA buffers (m-rows != 4b stay zero forever; fp8 0x00 == 0.0)
    for (int i = tid; i < 2048; i += 512) ((unsigned int*)(void*)hA)[i] = 0;
    __syncthreads();
    // h0 -> hA[0] at m-row 4b: byte(m,k) at (k>>7)*2048 + (((k>>5)&3)*16+m)*32 + (k&31)
    for (int i = tid; i < 1024; i += 512) {
        int b = i >> 8, c = i & 255;
        float hv = h0[(size_t)dir * B_SZ * HH + (size_t)(rq * 4 + b) * HH + c];
        hA[0][(c >> 7) * 2048 + (((c >> 5) & 3) * 16 + 4 * b) * 32 + (c & 31)] =
            (unsigned char)(__builtin_amdgcn_cvt_pk_fp8_f32(hv, hv, 0, false) & 0xff);
    }

    int grow = rq * 4 + quad;            // this lane's batch row (batch = quad)
    int elen = lens_sorted[grow];
    int maxlen = lens_sorted[rq * 4];    // sorted desc -> first of quad is max
    int col0 = 32 * wave + 2 * l16;      // adjacent pair (col0, col0+1)
    float2 cini = *(const float2*)(const void*)
        (c0 + (size_t)dir * B_SZ * HH + (size_t)grow * HH + col0);
    float c2[2] = {cini.x, cini.y};
    float* out_r = out + (size_t)grow * T_SZ * 512 + dir * HH + col0;
    // gates row-major: row base for batch grow, this lane's column pair
    const unsigned short* gbase0 = g3 + ((size_t)quad << 20) + col0;
    // LDS write offset for the (col0, col0+1) fp8 pair at m-row 4*quad
    int woff = (col0 >> 7) * 2048 + (((col0 >> 5) & 3) * 16 + 4 * quad) * 32 + (col0 & 31);

    // prefetch step-0 gate inputs: one pointer, 3 immediate-offset loads
    {
        int tr0 = dir ? (elen - 1) : 0;
        const unsigned short* rp = gbase0 + ((size_t)tr0 << 10);
        // loads below
        unsigned int t0 = *(const unsigned int*)(const void*)(rp);
        unsigned int t1 = *(const unsigned int*)(const void*)(rp + 256);
        unsigned int t2 = *(const unsigned int*)(const void*)(rp + 512);
        unsigned int t3 = *(const unsigned int*)(const void*)(rp + 768);
        __syncthreads();

        unsigned int gI = t0, gF = t1, gG = t2, gO = t3;
        const f32x4 zf = {0.f, 0.f, 0.f, 0.f};

        for (int s = 0; s < maxlen; ++s) {
            // A-fragments FIRST: h(s-1), 32B per K-chunk per lane, contiguous
            const unsigned char* Ab = hA[s & 1];
            v8i a0 = *(const v8i*)(const void*)(Ab + lane * 32);
            v8i a1 = *(const v8i*)(const void*)(Ab + 2048 + lane * 32);

            // prefetch NEXT step's gates (lands during this step's MFMAs)
            int trn = dir ? (elen - 2 - s) : (s + 1);
            trn = trn < 0 ? 0 : (trn > T_SZ - 1 ? T_SZ - 1 : trn);
            const unsigned short* rn = gbase0 + ((size_t)trn << 10);
            unsigned int nI = *(const unsigned int*)(const void*)(rn);
            unsigned int nF = *(const unsigned int*)(const void*)(rn + 256);
            unsigned int nG = *(const unsigned int*)(const void*)(rn + 512);
            unsigned int nO = *(const unsigned int*)(const void*)(rn + 768);

            f32x4 acc[4][2];
            // phase 1: all kc=0 MFMAs -- 8 independent, no stalls
            #pragma unroll
            for (int gb = 0; gb < 4; ++gb)
                #pragma unroll
                for (int p = 0; p < 2; ++p)
                    acc[gb][p] = __builtin_amdgcn_mfma_scale_f32_16x16x128_f8f6f4(
                        a0, regB[gb][p][0], zf, 0, 0, 0, 0x7F7F7F7F, 0, 0x7F7F7F7F);
            // phase 2: all kc=1 MFMAs -- each dep's kc=0 partner has retired;
            // o gate (gb=3) issued last so the i/f/g epilogue overlaps it
            #pragma unroll
            for (int gb = 0; gb < 4; ++gb)
                #pragma unroll
                for (int p = 0; p < 2; ++p)
                    acc[gb][p] = __builtin_amdgcn_mfma_scale_f32_16x16x128_f8f6f4(
                        a1, regB[gb][p][1], acc[gb][p], 0, 0, 0, 0x7F7F7F7F, 0, 0x7F7F7F7F);

            // c-state + tanh(c) need only i,f,g (overlaps o-gate MFMAs)
            float tc[2];
            #pragma unroll
            for (int p = 0; p < 2; ++p) {
                float iv = acc[0][p][0] + bf2f((unsigned short)(p ? (gI >> 16) : (gI & 0xffffu)));
                float fv = acc[1][p][0] + bf2f((unsigned short)(p ? (gF >> 16) : (gF & 0xffffu)));
                float gv = acc[2][p][0] + bf2f((unsigned short)(p ? (gG >> 16) : (gG & 0xffffu)));
                c2[p] = sigm(fv) * c2[p] + sigm(iv) * tanh_f(gv);
                tc[p] = tanh_f(c2[p]);
            }
            float ov0 = acc[3][0][0] + bf2f((unsigned short)(gO & 0xffffu));
            float ov1 = acc[3][1][0] + bf2f((unsigned short)(gO >> 16));
            float hv0 = sigm(ov0) * tc[0];
            float hv1 = sigm(ov1) * tc[1];

            // 2 fp8 bytes in one ushort store (cols col0, col0+1 LDS-adjacent)
            unsigned short pk = (unsigned short)
                (__builtin_amdgcn_cvt_pk_fp8_f32(hv0, hv1, 0, false) & 0xffffu);
            *(unsigned short*)(void*)(hA[(s + 1) & 1] + woff) = pk;
            if (s < elen) {
                int t_out = dir ? (elen - 1 - s) : s;
                *(float2*)(void*)(out_r + (size_t)t_out * 512) = make_float2(hv0, hv1);
            }
            gI = nI; gF = nF; gG = nG; gO = nO;
            // raw barrier: only the LDS h-write must drain; the out-store and
            // next-step gate loads stay in flight across the barrier.
            asm volatile("s_waitcnt lgkmcnt(0)" ::: "memory");
            __builtin_amdgcn_s_barrier();
        }
    }
}

// ---------------------------------------------------------------------------
// Workspace layout (bytes). gates_f overlaps dead a0/a1 regions.
// ---------------------------------------------------------------------------
#define OFF_XBF    ((size_t)0)
#define OFF_A0     ((size_t)5242880)
#define OFF_A1     ((size_t)38797312)
#define OFF_HBUF   ((size_t)72351744)
#define OFF_FEAT   ((size_t)89128960)
#define OFF_GF     OFF_A0                  /* 67,108,864 B over a0+a1 (dead) */
#define OFF_GB     ((size_t)139460608)
#define OFF_W0     ((size_t)206569472)
#define OFF_W1     ((size_t)206651392)
#define OFF_W2     ((size_t)207175680)
#define OFF_WIHF   ((size_t)207437824)
#define OFF_WIHB   ((size_t)209010688)
#define OFF_WFRAG  ((size_t)210583552)     /* 524288 B: fp8 Whh fragments f+b */
#define OFF_ORDER  ((size_t)212680704)
#define OFF_LENS   ((size_t)212680832)

extern "C" void kernel_launch(void* const* d_in, const int* in_sizes, int n_in,
                              void* d_out, int out_size, void* d_ws, size_t ws_size,
                              hipStream_t stream)
{
    const float* x    = (const float*)d_in[0];
    const int*   xlen = (const int*)d_in[1];
    const float* eW0  = (const float*)d_in[2];
    const float* eb0  = (const float*)d_in[3];
    const float* eW1  = (const float*)d_in[4];
    const float* eb1  = (const float*)d_in[5];
    const float* eW2  = (const float*)d_in[6];
    const float* eb2  = (const float*)d_in[7];
    const float* Wihf = (const float*)d_in[8];
    const float* Whhf = (const float*)d_in[9];
    const float* bihf = (const float*)d_in[10];
    const float* bhhf = (const float*)d_in[11];
    const float* Wihb = (const float*)d_in[12];
    const float* Whhb = (const float*)d_in[13];
    const float* bihb = (const float*)d_in[14];
    const float* bhhb = (const float*)d_in[15];
    const float* h0   = (const float*)d_in[16];
    const float* c0   = (const float*)d_in[17];
    float* out = (float*)d_out;

    char* ws = (char*)d_ws;
    unsigned short* xbf    = (unsigned short*)(ws + OFF_XBF);
    unsigned short* a0     = (unsigned short*)(ws + OFF_A0);
    unsigned short* a1     = (unsigned short*)(ws + OFF_A1);
    unsigned short* hbuf   = (unsigned short*)(ws + OFF_HBUF);
    unsigned short* feat   = (unsigned short*)(ws + OFF_FEAT);
    unsigned short* gatesF = (unsigned short*)(ws + OFF_GF);
    unsigned short* gatesB = (unsigned short*)(ws + OFF_GB);
    unsigned short* w0     = (unsigned short*)(ws + OFF_W0);
    unsigned short* w1     = (unsigned short*)(ws + OFF_W1);
    unsigned short* w2     = (unsigned short*)(ws + OFF_W2);
    unsigned short* wihf   = (unsigned short*)(ws + OFF_WIHF);
    unsigned short* wihb   = (unsigned short*)(ws + OFF_WIHB);
    unsigned char*  wfrag8 = (unsigned char*)(ws + OFF_WFRAG);
    int* order             = (int*)(ws + OFF_ORDER);
    int* lens_sorted       = (int*)(ws + OFF_LENS);

    // prep (weight conversions fused into 2 launches)
    k_cvt4<<<1024, 256, 0, stream>>>(x, xbf, B_SZ * T_SZ * DIN / 4);
    k_cvtw<<<512, 256, 0, stream>>>(eW0, w0, eW1, w1, eW2, w2, Wihf, wihf, Wihb, wihb);
    k_wfrag8<<<128, 256, 0, stream>>>(Whhf, Whhb, wfrag8);
    k_order<<<1, 64, 0, stream>>>(xlen, order, lens_sorted, out + (size_t)B_SZ * T_SZ * 512);
    k_ztail<<<dim3(T_SZ, B_SZ), 128, 0, stream>>>(lens_sorted, out);

    // encoder: 80 -> 512 -> 512 -> 256, ReLU each layer (row-major stores)
    k_gemm<<<dim3(1024, 4), 256, 0, stream>>>(xbf, w0, nullptr, eb0, a0, 32768, 512, 80, 1);
    k_gemm_t<<<dim3(4, 256), 256, 0, stream>>>(a0, w1, eb1, nullptr, a1,   512, 512, 1);
    k_gemm_t<<<dim3(2, 256), 256, 0, stream>>>(a1, w2, eb2, nullptr, hbuf, 256, 512, 1);

    // delta features + sort reorder -> feat[bs,t,768]
    k_deltas<<<32768, 256, 0, stream>>>(hbuf, order, feat);

    // gate inputs: feat @ Wih^T + (b_ih + b_hh), ROW-MAJOR [bs*1024+t][1024]
    // (both directions unreversed; backward reversal happens in the LSTM reads)
    k_gemm_t<<<dim3(8, 256), 256, 0, stream>>>(feat, wihf, bihf, bhhf, gatesF, 1024, 768, 0);
    k_gemm_t<<<dim3(8, 256), 256, 0, stream>>>(feat, wihb, bihb, bhhb, gatesB, 1024, 768, 0);

    // fp8 MX recurrence: 16 independent blocks (2 dirs x 8 batch quads), no sync
    k_lstm_fp8<<<dim3(8, 2), 512, 0, stream>>>(gatesF, gatesB, wfrag8, h0, c0,
                                               lens_sorted, out);
}

// Round 5
// 1214.754 us; speedup vs baseline: 2.0322x; 1.0176x over previous
//
#include <hip/hip_runtime.h>
#include <cstdint>
#include <cstddef>

// ---------------------------------------------------------------------------
// Problem constants
// ---------------------------------------------------------------------------
#define B_SZ 32
#define T_SZ 1024
#define DIN  80
#define H3   256   // encoder output dim
#define FEAT 768   // 3 * H3
#define G4   1024  // 4 * H (LSTM gates)
#define HH   256   // LSTM hidden

typedef __attribute__((ext_vector_type(8))) short short8;   // 8 x bf16 (4 VGPRs)
typedef __attribute__((ext_vector_type(4))) float f32x4;    // MFMA accumulator
typedef __attribute__((ext_vector_type(8))) int v8i;        // 32B fp8 fragment

__device__ inline float bf2f(unsigned short u) {
    return __uint_as_float(((unsigned int)u) << 16);
}
__device__ inline unsigned short f2bf(float f) {
    unsigned int u = __float_as_uint(f);
    u += 0x7fffu + ((u >> 16) & 1u);   // RNE
    return (unsigned short)(u >> 16);
}
// fast sigmoid/tanh: v_exp (exp2) + v_rcp
#define LOG2E 1.4426950408889634f
__device__ inline float sigm(float x) {
    return __builtin_amdgcn_rcpf(1.f + __builtin_amdgcn_exp2f(x * -LOG2E));
}
__device__ inline float tanh_f(float x) {
    return fmaf(2.f, __builtin_amdgcn_rcpf(1.f + __builtin_amdgcn_exp2f(x * (-2.f * LOG2E))), -1.f);
}

// async global->LDS, 16B per lane (dest must be linear: base + lane*16)
__device__ inline void gld16(const void* g, void* l) {
    __builtin_amdgcn_global_load_lds(
        (const __attribute__((address_space(1))) unsigned int*)g,
        (__attribute__((address_space(3))) unsigned int*)l, 16, 0, 0);
}

// ---------------------------------------------------------------------------
// fp32 -> bf16 conversion, float4-vectorized (n4 = n/4)
// ---------------------------------------------------------------------------
__device__ inline void cvt_seg(const float* __restrict__ s, unsigned short* __restrict__ d,
                               int n4, int i, int stride) {
    for (int k = i; k < n4; k += stride) {
        float4 f = ((const float4*)(const void*)s)[k];
        ushort4 u;
        u.x = f2bf(f.x); u.y = f2bf(f.y); u.z = f2bf(f.z); u.w = f2bf(f.w);
        ((ushort4*)(void*)d)[k] = u;
    }
}

// x + all five weight matrices + gate-bias sums + length argsort in ONE launch
__global__ void k_cvtw(const float* __restrict__ x,  unsigned short* __restrict__ xbf,
                       const float* __restrict__ s0, unsigned short* __restrict__ d0,
                       const float* __restrict__ s1, unsigned short* __restrict__ d1,
                       const float* __restrict__ s2, unsigned short* __restrict__ d2,
                       const float* __restrict__ s3, unsigned short* __restrict__ d3,
                       const float* __restrict__ s4, unsigned short* __restrict__ d4,
                       const float* __restrict__ bihf, const float* __restrict__ bhhf,
                       const float* __restrict__ bihb, const float* __restrict__ bhhb,
                       float* __restrict__ bsum,
                       const int* __restrict__ lens, int* __restrict__ order,
                       int* __restrict__ lens_sorted, float* __restrict__ out_order) {
    int i = blockIdx.x * 256 + threadIdx.x;
    int stride = gridDim.x * 256;
    cvt_seg(x,  xbf, 655360, i, stride);  // 32*1024*80 / 4
    cvt_seg(s0, d0, 10240,  i, stride);   // 512*80
    cvt_seg(s1, d1, 65536,  i, stride);   // 512*512
    cvt_seg(s2, d2, 32768,  i, stride);   // 256*512
    cvt_seg(s3, d3, 196608, i, stride);   // 1024*768
    cvt_seg(s4, d4, 196608, i, stride);   // 1024*768
    if (i < 2048)
        bsum[i] = (i < 1024) ? (bihf[i] + bhhf[i]) : (bihb[i - 1024] + bhhb[i - 1024]);
    if (i < B_SZ) {   // stable argsort by descending length (block 0 only)
        int lb = lens[i];
        int r = 0;
        for (int j = 0; j < B_SZ; ++j) {
            int lj = lens[j];
            if (lj > lb || (lj == lb && j < i)) ++r;
        }
        order[r] = i;
        lens_sorted[r] = lb;
        out_order[r] = (float)i;   // second tuple output, as float
    }
}

// zero the padded tail: out[bs, t, 0:512] = 0 for t >= len[bs]
__global__ void k_ztail(const int* __restrict__ lens_sorted, float* __restrict__ out) {
    int t = blockIdx.x, bs = blockIdx.y;
    if (t < lens_sorted[bs]) return;
    float4* p = (float4*)(out + ((size_t)bs * T_SZ + t) * 512);
    p[threadIdx.x] = make_float4(0.f, 0.f, 0.f, 0.f);   // 128 threads x 16B
}

// ---------------------------------------------------------------------------
// Whh [1024 rows (n), 256 cols (k)] fp32 -> fp8 e4m3 in MFMA B-fragment order
// for mfma_scale_f32_16x16x128_f8f6f4, IDENTITY n mapping (one col per lane):
//   slot (nt, kc): n = nt*16 + (lane&15), k = kc*128 + (lane>>4)*32 + j
// byte addr = ((nt*2 + kc)*64 + lane)*32. One thread per 16-byte half.
// Both directions in one launch: grid 128, dir = blockIdx.x >= 64.
// ---------------------------------------------------------------------------
__global__ void k_wfrag8(const float* __restrict__ Whhf, const float* __restrict__ Whhb,
                         unsigned char* __restrict__ dst) {
    int t = blockIdx.x * 256 + threadIdx.x;   // 0..32767
    int dir = t >> 14;
    t &= 16383;
    const float* Whh = dir ? Whhb : Whhf;
    unsigned char* d = dst + (size_t)dir * 262144;
    int lane = t & 63, hf = (t >> 6) & 1, kc = (t >> 7) & 1, nt = t >> 8;
    int n = nt * 16 + (lane & 15);
    int k0 = kc * 128 + (lane >> 4) * 32 + hf * 16;
    const float* p = Whh + (size_t)n * 256 + k0;
    unsigned int o[4];
    #pragma unroll
    for (int q = 0; q < 4; ++q) {
        float4 f = *(const float4*)(const void*)(p + 4 * q);
        o[q] = (__builtin_amdgcn_cvt_pk_fp8_f32(f.x, f.y, 0, false) & 0xffff)
             | (__builtin_amdgcn_cvt_pk_fp8_f32(f.z, f.w, 0, false) << 16);
    }
    int slot = (nt * 2 + kc) * 64 + lane;
    *(uint4*)(void*)(d + (size_t)slot * 32 + hf * 16) = make_uint4(o[0], o[1], o[2], o[3]);
}

// ---------------------------------------------------------------------------
// direct bf16 MFMA GEMM (kept only for K=80 encoder layer 0)
// Block tile 32(M) x 128(N), 4 waves (2x2), each wave 16x64 via 4 accums.
// ---------------------------------------------------------------------------
__global__ __launch_bounds__(256) void k_gemm(
    const unsigned short* __restrict__ A, const unsigned short* __restrict__ Bw,
    const float* __restrict__ bias,
    unsigned short* __restrict__ C, int M, int N, int K, int relu)
{
    int tid  = threadIdx.x;
    int lane = tid & 63;
    int wave = tid >> 6;
    int waveM = wave >> 1, waveN = wave & 1;
    int l16  = lane & 15;
    int quad = lane >> 4;
    int mBase = blockIdx.x * 32 + waveM * 16;
    int nBase = blockIdx.y * 128 + waveN * 64;

    const unsigned short* pA  = A  + (size_t)(mBase + l16) * K + quad * 8;
    const unsigned short* pB0 = Bw + (size_t)(nBase +  0 + l16) * K + quad * 8;
    const unsigned short* pB1 = Bw + (size_t)(nBase + 16 + l16) * K + quad * 8;
    const unsigned short* pB2 = Bw + (size_t)(nBase + 32 + l16) * K + quad * 8;
    const unsigned short* pB3 = Bw + (size_t)(nBase + 48 + l16) * K + quad * 8;

    const short8 z8 = {0, 0, 0, 0, 0, 0, 0, 0};
    f32x4 acc0 = {0.f, 0.f, 0.f, 0.f};
    f32x4 acc1 = acc0, acc2 = acc0, acc3 = acc0;

    for (int k0 = 0; k0 < K; k0 += 32) {
        bool ok = (k0 + quad * 8) < K;
        short8 av  = ok ? *(const short8*)(const void*)(pA  + k0) : z8;
        short8 bv0 = ok ? *(const short8*)(const void*)(pB0 + k0) : z8;
        short8 bv1 = ok ? *(const short8*)(const void*)(pB1 + k0) : z8;
        short8 bv2 = ok ? *(const short8*)(const void*)(pB2 + k0) : z8;
        short8 bv3 = ok ? *(const short8*)(const void*)(pB3 + k0) : z8;
        acc0 = __builtin_amdgcn_mfma_f32_16x16x32_bf16(av, bv0, acc0, 0, 0, 0);
        acc1 = __builtin_amdgcn_mfma_f32_16x16x32_bf16(av, bv1, acc1, 0, 0, 0);
        acc2 = __builtin_amdgcn_mfma_f32_16x16x32_bf16(av, bv2, acc2, 0, 0, 0);
        acc3 = __builtin_amdgcn_mfma_f32_16x16x32_bf16(av, bv3, acc3, 0, 0, 0);
    }

    int rowD = mBase + quad * 4;
    #pragma unroll
    for (int nt = 0; nt < 4; ++nt) {
        int col = nBase + nt * 16 + l16;
        float bsum = bias ? bias[col] : 0.f;
        f32x4 a = (nt == 0) ? acc0 : (nt == 1) ? acc1 : (nt == 2) ? acc2 : acc3;
        #pragma unroll
        for (int r = 0; r < 4; ++r) {
            float v = a[r] + bsum;
            if (relu) v = v > 0.f ? v : 0.f;
            C[(size_t)(rowD + r) * N + col] = f2bf(v);
        }
    }
}

// ---------------------------------------------------------------------------
// LDS-staged bf16 MFMA GEMM (m97 structure: 128x128 tile, BK=32,
// global_load_lds width 16, 2 barriers/K-step). K multiple of 32,
// M and N multiples of 128. grid = (N/128, M/128).
// C[M,N] = act(A[M,K] @ Bw[N,K]^T + bias), bf16 out, row stride ldc.
// Split-output mode (C2 != null): global cols >= 1024 go to C2 at col-1024
// (used by the merged forward+backward gates GEMM; both halves keep their
// original [32768][1024] layout so the LSTM indexing is unchanged).
// ---------------------------------------------------------------------------
__global__ __launch_bounds__(256) void k_gemm_t(
    const unsigned short* __restrict__ A, const unsigned short* __restrict__ Bw,
    const float* __restrict__ bias,
    unsigned short* __restrict__ C, unsigned short* __restrict__ C2,
    int N, int K, int ldc, int relu)
{
    __shared__ unsigned short lA[128 * 32];
    __shared__ unsigned short lB[128 * 32];
    int tid  = threadIdx.x;
    int lane = tid & 63;
    int wave = tid >> 6;
    int l16  = lane & 15, quad = lane >> 4;
    int wm = wave >> 1, wn = wave & 1;
    size_t mBase = (size_t)blockIdx.y * 128;
    size_t nBase = (size_t)blockIdx.x * 128;

    int c0 = tid, c1 = tid + 256;
    const unsigned short* sA0 = A  + (mBase + (c0 >> 2)) * K + (c0 & 3) * 8;
    const unsigned short* sA1 = A  + (mBase + (c1 >> 2)) * K + (c1 & 3) * 8;
    const unsigned short* sB0 = Bw + (nBase + (c0 >> 2)) * K + (c0 & 3) * 8;
    const unsigned short* sB1 = Bw + (nBase + (c1 >> 2)) * K + (c1 & 3) * 8;
    unsigned short* dA0 = lA + c0 * 8;
    unsigned short* dA1 = lA + c1 * 8;
    unsigned short* dB0 = lB + c0 * 8;
    unsigned short* dB1 = lB + c1 * 8;

    f32x4 acc[4][4];
    #pragma unroll
    for (int i = 0; i < 4; ++i)
        #pragma unroll
        for (int j = 0; j < 4; ++j) acc[i][j] = (f32x4){0.f, 0.f, 0.f, 0.f};

    const unsigned short* la = lA + (wm * 64 + l16) * 32 + quad * 8;
    const unsigned short* lb = lB + (wn * 64 + l16) * 32 + quad * 8;

    for (int k0 = 0; k0 < K; k0 += 32) {
        gld16(sA0 + k0, dA0);
        gld16(sA1 + k0, dA1);
        gld16(sB0 + k0, dB0);
        gld16(sB1 + k0, dB1);
        __syncthreads();                 // vmcnt(0) drain + barrier: tile ready
        short8 af[4], bf[4];
        #pragma unroll
        for (int i = 0; i < 4; ++i) {
            af[i] = *(const short8*)(const void*)(la + i * 16 * 32);
            bf[i] = *(const short8*)(const void*)(lb + i * 16 * 32);
        }
        #pragma unroll
        for (int i = 0; i < 4; ++i)
            #pragma unroll
            for (int j = 0; j < 4; ++j)
                acc[i][j] = __builtin_amdgcn_mfma_f32_16x16x32_bf16(af[i], bf[j], acc[i][j], 0, 0, 0);
        __syncthreads();                 // frags consumed before next overwrite
    }

    #pragma unroll
    for (int j = 0; j < 4; ++j) {
        int colg = (int)nBase + wn * 64 + j * 16 + l16;
        float bsum = bias[colg];
        unsigned short* dst = C;
        int cg = colg;
        if (C2 && colg >= 1024) { dst = C2; cg = colg - 1024; }
        #pragma unroll
        for (int i = 0; i < 4; ++i) {
            int row = (int)mBase + wm * 64 + i * 16 + quad * 4;
            #pragma unroll
            for (int r = 0; r < 4; ++r) {
                float v = acc[i][j][r] + bsum;
                if (relu) v = v > 0.f ? v : 0.f;
                dst[(size_t)(row + r) * ldc + cg] = f2bf(v);
            }
        }
    }
}

// ---------------------------------------------------------------------------
// delta features + batch reorder (unchanged)
// ---------------------------------------------------------------------------
__global__ void k_deltas(const unsigned short* __restrict__ hbuf, const int* __restrict__ order,
                         unsigned short* __restrict__ feat)
{
    int bt = blockIdx.x;        // bs*1024 + t
    int c  = threadIdx.x;       // 0..255
    int bs = bt >> 10, t = bt & 1023;
    int b  = order[bs];
    const unsigned short* hb = hbuf + (size_t)b * T_SZ * H3 + c;

    float hv[9];
    #pragma unroll
    for (int d = -4; d <= 4; ++d) {
        int tt = t + d;
        tt = tt < 0 ? 0 : (tt > T_SZ - 1 ? T_SZ - 1 : tt);
        hv[d + 4] = bf2f(hb[(size_t)tt * H3]);
    }
    float d1v[5];
    #pragma unroll
    for (int s = -2; s <= 2; ++s) {
        d1v[s + 2] = (hv[s + 5] - hv[s + 3]) * 0.5f + (hv[s + 6] - hv[s + 2]) * 0.25f;
    }
    int sp1 = (t + 1 > T_SZ - 1 ? T_SZ - 1 : t + 1) - t;
    int sm1 = (t - 1 < 0 ? 0 : t - 1) - t;
    int sp2 = (t + 2 > T_SZ - 1 ? T_SZ - 1 : t + 2) - t;
    int sm2 = (t - 2 < 0 ? 0 : t - 2) - t;
    float d2 = (d1v[2 + sp1] - d1v[2 + sm1]) * 0.5f + (d1v[2 + sp2] - d1v[2 + sm2]) * 0.25f;

    size_t fb = (size_t)bt * FEAT;
    feat[fb + c]       = hb[(size_t)t * H3];
    feat[fb + 256 + c] = f2bf(d1v[2]);
    feat[fb + 512 + c] = f2bf(d2);
}

// ---------------------------------------------------------------------------
// fp8 MX-MFMA LSTM recurrence v9: grid (rq 0..7, dir 0..1) = 16 blocks,
// 1024 THREADS (16 waves, 4 waves/SIMD) -- was 512 (2 waves/SIMD).
// Changes vs v8 (phase-split was neutral; the stall is latency exposure
// with only 2 lockstep waves/SIMD, not MFMA issue order):
//  - wave w owns h-cols [16w, 16w+15]; each lane owns ONE column:
//    per-lane epilogue tail halves (5 transcendental pairs, 1 fp8 byte,
//    1 float store); 4 waves/SIMD hide trans-chain + ds_read latency.
//  - regB: 4 gb x 2 kc x 32B = 64 VGPRs (was 128) -> fits 128-VGPR
//    budget needed for 16 waves at 2 blocks/CU.
//  - gate input rides in as the MFMA C-operand (element 0 = m-row 4*quad,
//    this lane's batch): post-MFMA adds removed from the tail.
//  - MFMA pipe/SIMD unchanged (4 waves x 8 = 32 MFMAs = same 128/block).
// ---------------------------------------------------------------------------
__global__ __launch_bounds__(1024, 4) void k_lstm_fp8(
    const unsigned short* __restrict__ g3f, const unsigned short* __restrict__ g3b,
    const unsigned char* __restrict__ wfrag8,
    const float* __restrict__ h0, const float* __restrict__ c0,
    const int* __restrict__ lens_sorted, float* __restrict__ out)
{
    int rq = blockIdx.x, dir = blockIdx.y;
    const unsigned short* g3 = (dir ? g3b : g3f) + (size_t)rq * 4194304;
    const unsigned char* wsrc = wfrag8 + (size_t)dir * 262144;

    __shared__ __align__(16) unsigned char hA[2][4096];

    int tid = threadIdx.x;
    int w = tid >> 6, lane = tid & 63;
    int l16 = lane & 15, quad = lane >> 4;

    // Whh fragments for this wave's 16 columns: regB[gb][kc], nt = gb*16 + w
    v8i regB[4][2];
    #pragma unroll
    for (int gb = 0; gb < 4; ++gb)
        #pragma unroll
        for (int kc = 0; kc < 2; ++kc) {
            int nt = gb * 16 + w;
            regB[gb][kc] = *(const v8i*)(const void*)
                (wsrc + ((size_t)((nt * 2 + kc) * 64 + lane)) * 32);
        }

    // zero both hA buffers (m-rows != 4b stay zero forever; fp8 0x00 == 0.0)
    for (int i = tid; i < 2048; i += 1024) ((unsigned int*)(void*)hA)[i] = 0;
    __syncthreads();
    // h0 -> hA[0] at m-row 4b: byte(m,k) at (k>>7)*2048 + (((k>>5)&3)*16+m)*32 + (k&31)
    {
        int b = tid >> 8, c = tid & 255;
        float hv = h0[(size_t)dir * B_SZ * HH + (size_t)(rq * 4 + b) * HH + c];
        hA[0][(c >> 7) * 2048 + (((c >> 5) & 3) * 16 + 4 * b) * 32 + (c & 31)] =
            (unsigned char)(__builtin_amdgcn_cvt_pk_fp8_f32(hv, hv, 0, false) & 0xff);
    }

    int grow = rq * 4 + quad;            // this lane's batch row (batch = quad)
    int elen = lens_sorted[grow];
    int maxlen = lens_sorted[rq * 4];    // sorted desc -> first of quad is max
    int col = w * 16 + l16;              // this lane's single h column
    float c2 = c0[(size_t)dir * B_SZ * HH + (size_t)grow * HH + col];
    float* out_r = out + (size_t)grow * T_SZ * 512 + dir * HH + col;
    // gates row-major [row = bs*1024 + t][1024]; this lane's column
    const unsigned short* gb0 = g3 + ((size_t)quad << 20) + col;
    // LDS write offset for this lane's fp8 h byte at m-row 4*quad
    int woff = (col >> 7) * 2048 + (((col >> 5) & 3) * 16 + 4 * quad) * 32 + (col & 31);

    // prefetch step-0 gate inputs (4 ushorts: one per gate, 512B apart)
    int tr0 = dir ? (elen - 1) : 0;
    const unsigned short* rp = gb0 + ((size_t)tr0 << 10);
    unsigned short gI = rp[0], gF = rp[256], gG = rp[512], gO = rp[768];
    __syncthreads();

    for (int s = 0; s < maxlen; ++s) {
        // A-fragments FIRST: h(s-1), 32B per K-chunk per lane, contiguous
        const unsigned char* Ab = hA[s & 1];
        v8i a0 = *(const v8i*)(const void*)(Ab + lane * 32);
        v8i a1 = *(const v8i*)(const void*)(Ab + 2048 + lane * 32);

        // prefetch NEXT step's gates (lands during this step's MFMAs)
        int trn = dir ? (elen - 2 - s) : (s + 1);
        trn = trn < 0 ? 0 : (trn > T_SZ - 1 ? T_SZ - 1 : trn);
        const unsigned short* rn = gb0 + ((size_t)trn << 10);
        unsigned short nI = rn[0], nF = rn[256], nG = rn[512], nO = rn[768];

        // gate input enters as the C-operand (element 0 = row 4*quad = batch)
        f32x4 acc[4];
        acc[0] = (f32x4){bf2f(gI), 0.f, 0.f, 0.f};
        acc[1] = (f32x4){bf2f(gF), 0.f, 0.f, 0.f};
        acc[2] = (f32x4){bf2f(gG), 0.f, 0.f, 0.f};
        acc[3] = (f32x4){bf2f(gO), 0.f, 0.f, 0.f};
        #pragma unroll
        for (int gb = 0; gb < 4; ++gb)
            acc[gb] = __builtin_amdgcn_mfma_scale_f32_16x16x128_f8f6f4(
                a0, regB[gb][0], acc[gb], 0, 0, 0, 0x7F7F7F7F, 0, 0x7F7F7F7F);
        #pragma unroll
        for (int gb = 0; gb < 4; ++gb)   // o gate (gb=3) last
            acc[gb] = __builtin_amdgcn_mfma_scale_f32_16x16x128_f8f6f4(
                a1, regB[gb][1], acc[gb], 0, 0, 0, 0x7F7F7F7F, 0, 0x7F7F7F7F);

        // epilogue: ONE h value per lane
        c2 = sigm(acc[1][0]) * c2 + sigm(acc[0][0]) * tanh_f(acc[2][0]);
        float tc = tanh_f(c2);
        float hv = sigm(acc[3][0]) * tc;

        hA[(s + 1) & 1][woff] =
            (unsigned char)(__builtin_amdgcn_cvt_pk_fp8_f32(hv, hv, 0, false) & 0xff);
        if (s < elen) {
            int t_out = dir ? (elen - 1 - s) : s;
            out_r[(size_t)t_out * 512] = hv;
        }
        gI = nI; gF = nF; gG = nG; gO = nO;
        // raw barrier: only the LDS h-write must drain; the out-store and
        // next-step gate loads stay in flight across the barrier.
        asm volatile("s_waitcnt lgkmcnt(0)" ::: "memory");
        __builtin_amdgcn_s_barrier();
    }
}

// ---------------------------------------------------------------------------
// Workspace layout (bytes). gates_f overlaps dead a0/a1 regions.
// ---------------------------------------------------------------------------
#define OFF_XBF    ((size_t)0)
#define OFF_A0     ((size_t)5242880)
#define OFF_A1     ((size_t)38797312)
#define OFF_HBUF   ((size_t)72351744)
#define OFF_FEAT   ((size_t)89128960)
#define OFF_GF     OFF_A0                  /* 67,108,864 B over a0+a1 (dead) */
#define OFF_GB     ((size_t)139460608)
#define OFF_W0     ((size_t)206569472)
#define OFF_W1     ((size_t)206651392)
#define OFF_W2     ((size_t)207175680)
#define OFF_WIHF   ((size_t)207437824)
#define OFF_WIHB   ((size_t)209010688)     /* contiguous after WIHF (merged B) */
#define OFF_WFRAG  ((size_t)210583552)     /* 524288 B: fp8 Whh fragments f+b */
#define OFF_BSUM   ((size_t)211107840)     /* float[2048] gate bias sums */
#define OFF_ORDER  ((size_t)212680704)
#define OFF_LENS   ((size_t)212680832)

extern "C" void kernel_launch(void* const* d_in, const int* in_sizes, int n_in,
                              void* d_out, int out_size, void* d_ws, size_t ws_size,
                              hipStream_t stream)
{
    const float* x    = (const float*)d_in[0];
    const int*   xlen = (const int*)d_in[1];
    const float* eW0  = (const float*)d_in[2];
    const float* eb0  = (const float*)d_in[3];
    const float* eW1  = (const float*)d_in[4];
    const float* eb1  = (const float*)d_in[5];
    const float* eW2  = (const float*)d_in[6];
    const float* eb2  = (const float*)d_in[7];
    const float* Wihf = (const float*)d_in[8];
    const float* Whhf = (const float*)d_in[9];
    const float* bihf = (const float*)d_in[10];
    const float* bhhf = (const float*)d_in[11];
    const float* Wihb = (const float*)d_in[12];
    const float* Whhb = (const float*)d_in[13];
    const float* bihb = (const float*)d_in[14];
    const float* bhhb = (const float*)d_in[15];
    const float* h0   = (const float*)d_in[16];
    const float* c0   = (const float*)d_in[17];
    float* out = (float*)d_out;

    char* ws = (char*)d_ws;
    unsigned short* xbf    = (unsigned short*)(ws + OFF_XBF);
    unsigned short* a0     = (unsigned short*)(ws + OFF_A0);
    unsigned short* a1     = (unsigned short*)(ws + OFF_A1);
    unsigned short* hbuf   = (unsigned short*)(ws + OFF_HBUF);
    unsigned short* feat   = (unsigned short*)(ws + OFF_FEAT);
    unsigned short* gatesF = (unsigned short*)(ws + OFF_GF);
    unsigned short* gatesB = (unsigned short*)(ws + OFF_GB);
    unsigned short* w0     = (unsigned short*)(ws + OFF_W0);
    unsigned short* w1     = (unsigned short*)(ws + OFF_W1);
    unsigned short* w2     = (unsigned short*)(ws + OFF_W2);
    unsigned short* wihf   = (unsigned short*)(ws + OFF_WIHF);
    unsigned short* wihb   = (unsigned short*)(ws + OFF_WIHB);
    unsigned char*  wfrag8 = (unsigned char*)(ws + OFF_WFRAG);
    float* bsum            = (float*)(ws + OFF_BSUM);
    int* order             = (int*)(ws + OFF_ORDER);
    int* lens_sorted       = (int*)(ws + OFF_LENS);

    // prep: all conversions + bias sums + argsort in two launches
    k_cvtw<<<1024, 256, 0, stream>>>(x, xbf, eW0, w0, eW1, w1, eW2, w2,
                                     Wihf, wihf, Wihb, wihb,
                                     bihf, bhhf, bihb, bhhb, bsum,
                                     xlen, order, lens_sorted,
                                     out + (size_t)B_SZ * T_SZ * 512);
    k_wfrag8<<<128, 256, 0, stream>>>(Whhf, Whhb, wfrag8);
    k_ztail<<<dim3(T_SZ, B_SZ), 128, 0, stream>>>(lens_sorted, out);

    // encoder: 80 -> 512 -> 512 -> 256, ReLU each layer (row-major stores)
    k_gemm<<<dim3(1024, 4), 256, 0, stream>>>(xbf, w0, eb0, a0, 32768, 512, 80, 1);
    k_gemm_t<<<dim3(4, 256), 256, 0, stream>>>(a0, w1, eb1, a1,   nullptr, 512, 512, 512, 1);
    k_gemm_t<<<dim3(2, 256), 256, 0, stream>>>(a1, w2, eb2, hbuf, nullptr, 256, 512, 256, 1);

    // delta features + sort reorder -> feat[bs,t,768]
    k_deltas<<<32768, 256, 0, stream>>>(hbuf, order, feat);

    // gate inputs, BOTH directions in one GEMM: B = [wihf; wihb] (adjacent in
    // ws), cols < 1024 -> gatesF, >= 1024 -> gatesB (each [32768][1024]).
    k_gemm_t<<<dim3(16, 256), 256, 0, stream>>>(feat, wihf, bsum, gatesF, gatesB,
                                                2048, 768, 1024, 0);

    // fp8 MX recurrence: 16 independent blocks (2 dirs x 8 batch quads), no sync
    k_lstm_fp8<<<dim3(8, 2), 1024, 0, stream>>>(gatesF, gatesB, wfrag8, h0, c0,
                                                lens_sorted, out);
}